// Round 7
// baseline (160.170 us; speedup 1.0000x reference)
//
#include <hip/hip_runtime.h>
#include <math.h>

#define PI_F 3.14159265358979323846f
#define KSTEP 0.21959209425992272f /* (log2(224)-1)/31 */

using bf16x8 = __attribute__((ext_vector_type(8))) short;
using f32x4 = __attribute__((ext_vector_type(4))) float;
using u16x8 = __attribute__((ext_vector_type(8))) unsigned short;

static __device__ __forceinline__ float wave_reduce_sum(float v) {
#pragma unroll
  for (int off = 32; off; off >>= 1) v += __shfl_down(v, off);
  return v;
}

static __device__ __forceinline__ unsigned short f2bf(float f) {
  unsigned u = __float_as_uint(f);
  return (unsigned short)((u + 0x7fffu + ((u >> 16) & 1u)) >> 16);
}

static __device__ __forceinline__ float bf2f(unsigned short s) {
  return __uint_as_float(((unsigned)s) << 16);
}

static __device__ __forceinline__ void gload_lds16(const void* g, void* l) {
  __builtin_amdgcn_global_load_lds((const __attribute__((address_space(1))) unsigned int*)g,
                                   (__attribute__((address_space(3))) unsigned int*)l, 16, 0, 0);
}

// ---- fused prep: x->bf16 x_t + t_mean | wkT (transposed Wk + bias row) | sc table ----
__global__ __launch_bounds__(256) void prep_kernel(const float* __restrict__ x,
                                                   const float* __restrict__ qkv_w,
                                                   const float* __restrict__ qkv_b,
                                                   unsigned short* __restrict__ xt,
                                                   float* __restrict__ t_mean,
                                                   unsigned short* __restrict__ wkT,
                                                   float2* __restrict__ sc) {
  const int bid = blockIdx.x;
  const int t = threadIdx.x;
  __shared__ float tile[64 * 33];
  __shared__ float tl2[64 * 65];
  if (bid < 1024) {
    const int ct = bid & 15, b = bid >> 4;
    const int cl = t >> 2, pq = (t & 3) * 8;  // read role
    const int pl = t >> 3, cq = (t & 7) * 8;  // write role
    float sum = 0.0f;
    const float* xrow = x + ((size_t)(b * 1024 + ct * 64 + cl) * 256) + pq;
    unsigned short* xtb = xt + (size_t)b * 262144 + ct * 64;
    for (int pt = 0; pt < 8; ++pt) {
      const float4 v0 = *reinterpret_cast<const float4*>(xrow + pt * 32);
      const float4 v1 = *reinterpret_cast<const float4*>(xrow + pt * 32 + 4);
      tile[cl * 33 + pq + 0] = v0.x; tile[cl * 33 + pq + 1] = v0.y;
      tile[cl * 33 + pq + 2] = v0.z; tile[cl * 33 + pq + 3] = v0.w;
      tile[cl * 33 + pq + 4] = v1.x; tile[cl * 33 + pq + 5] = v1.y;
      tile[cl * 33 + pq + 6] = v1.z; tile[cl * 33 + pq + 7] = v1.w;
      sum += (v0.x + v0.y) + (v0.z + v0.w) + (v1.x + v1.y) + (v1.z + v1.w);
      __syncthreads();
      u16x8 o;
#pragma unroll
      for (int e = 0; e < 8; ++e) o[e] = f2bf(tile[(cq + e) * 33 + pl]);
      *reinterpret_cast<u16x8*>(xtb + (size_t)(pt * 32 + pl) * 1024 + cq) = o;
      __syncthreads();
    }
    sum += __shfl_xor(sum, 1);
    sum += __shfl_xor(sum, 2);
    if ((t & 3) == 0) t_mean[b * 1024 + ct * 64 + cl] = sum * (1.0f / 256.0f);
  } else if (bid < 1280) {
    // wkT[h][c][d] transpose tiles: bf16, c rows, d contiguous
    const int bb = bid - 1024;
    const int h = bb >> 5, t5 = bb & 31;
    const int dt = t5 >> 4, ct = t5 & 15;
    {
      const int dl = t >> 2, cq = (t & 3) * 16;
      const float* src = qkv_w + (size_t)(1024 + h * 128 + dt * 64 + dl) * 1024 + ct * 64 + cq;
#pragma unroll
      for (int i = 0; i < 4; ++i) {
        const float4 v = *reinterpret_cast<const float4*>(src + i * 4);
        tl2[dl * 65 + cq + i * 4 + 0] = v.x; tl2[dl * 65 + cq + i * 4 + 1] = v.y;
        tl2[dl * 65 + cq + i * 4 + 2] = v.z; tl2[dl * 65 + cq + i * 4 + 3] = v.w;
      }
    }
    __syncthreads();
    {
      const int cl = t >> 2, dq = (t & 3) * 16;
      unsigned short* dst = wkT + (size_t)(h * 1152 + ct * 64 + cl) * 128 + dt * 64 + dq;
      u16x8 o0, o1;
#pragma unroll
      for (int e = 0; e < 8; ++e) {
        o0[e] = f2bf(tl2[(dq + e) * 65 + cl]);
        o1[e] = f2bf(tl2[(dq + 8 + e) * 65 + cl]);
      }
      *reinterpret_cast<u16x8*>(dst) = o0;
      *reinterpret_cast<u16x8*>(dst + 8) = o1;
    }
  } else if (bid < 1288) {
    // wkT rows 1024..1151: row 1024 = k-bias, rest zero
    const int h = bid - 1280;
    for (int idx = t; idx < 16384; idx += 256) {
      const int row = 1024 + (idx >> 7), d = idx & 127;
      unsigned short v = 0;
      if (row == 1024) v = f2bf(qkv_b[1024 + h * 128 + d]);
      wkT[(size_t)(h * 1152 + row) * 128 + d] = v;
    }
  } else {
    const int idx = (bid - 1288) * 256 + t;  // 16384
    const int m = idx >> 8, j = idx & 255;
    const float band = exp2f((float)(m & 31) * KSTEP) * PI_F;
    const float coord = (m < 32) ? (-1.0f + (2.0f / 15.0f) * (float)(j >> 4))
                                 : (-1.0f + (2.0f / 15.0f) * (float)(j & 15));
    float sn, cs;
    sincosf(coord * band, &sn, &cs);
    sc[idx] = make_float2(sn, cs);
  }
}

// ---------------- split-K skinny GEMM: Cp[kc] = A * B^T (K-chunk = 256) ----------------
__global__ __launch_bounds__(256) void gemm_splitk(
    const float* __restrict__ A, int lda, int aStrideZ,
    const float* __restrict__ B, int ldb, int bStrideZ,
    float* __restrict__ Cp, int ldc, int cStrideZ, int cStrideKc, int KC) {
  const int nt = blockIdx.x, mt = blockIdx.y;
  const int z = blockIdx.z / KC, kc = blockIdx.z % KC;
  const int tid = threadIdx.x;
  A += (size_t)z * aStrideZ + (size_t)mt * 32 * lda + kc * 256;
  B += (size_t)z * bStrideZ + (size_t)nt * 64 * ldb + kc * 256;
  Cp += (size_t)kc * cStrideKc + (size_t)z * cStrideZ + (size_t)mt * 32 * ldc + nt * 64;

  __shared__ float As[32][34];
  __shared__ float Bs[32][68];

  const int tm = tid >> 4;
  const int tn = tid & 15;
  float acc0[4] = {0, 0, 0, 0}, acc1[4] = {0, 0, 0, 0};

  for (int k0 = 0; k0 < 256; k0 += 32) {
    {
      const int m = tid >> 3, kq = tid & 7;
      float4 v = *reinterpret_cast<const float4*>(A + (size_t)m * lda + k0 + kq * 4);
      As[kq * 4 + 0][m] = v.x; As[kq * 4 + 1][m] = v.y;
      As[kq * 4 + 2][m] = v.z; As[kq * 4 + 3][m] = v.w;
    }
#pragma unroll
    for (int r = 0; r < 2; ++r) {
      const int idx = r * 256 + tid;
      const int n = idx >> 3, kq = idx & 7;
      float4 v = *reinterpret_cast<const float4*>(B + (size_t)n * ldb + k0 + kq * 4);
      Bs[kq * 4 + 0][n] = v.x; Bs[kq * 4 + 1][n] = v.y;
      Bs[kq * 4 + 2][n] = v.z; Bs[kq * 4 + 3][n] = v.w;
    }
    __syncthreads();
#pragma unroll
    for (int k = 0; k < 32; ++k) {
      const float a0 = As[k][tm * 2], a1 = As[k][tm * 2 + 1];
      const float4 bb = *reinterpret_cast<const float4*>(&Bs[k][tn * 4]);
      acc0[0] += a0 * bb.x; acc0[1] += a0 * bb.y; acc0[2] += a0 * bb.z; acc0[3] += a0 * bb.w;
      acc1[0] += a1 * bb.x; acc1[1] += a1 * bb.y; acc1[2] += a1 * bb.z; acc1[3] += a1 * bb.w;
    }
    __syncthreads();
  }
  *reinterpret_cast<float4*>(Cp + (size_t)(tm * 2) * ldc + tn * 4) =
      make_float4(acc0[0], acc0[1], acc0[2], acc0[3]);
  *reinterpret_cast<float4*>(Cp + (size_t)(tm * 2 + 1) * ldc + tn * 4) =
      make_float4(acc1[0], acc1[1], acc1[2], acc1[3]);
}

// ---------------- proj GEMM with inline 4-partial A reduce + Wv-bias ----------------
__global__ __launch_bounds__(256) void gemm_proj_splitk(
    const float* __restrict__ Apart, const float* __restrict__ abias,
    const float* __restrict__ B, float* __restrict__ Cp) {
  const int nt = blockIdx.x, mt = blockIdx.y, kc = blockIdx.z;
  const int tid = threadIdx.x;
  B += (size_t)nt * 64 * 1024 + kc * 256;
  Cp += (size_t)kc * 65536 + (size_t)mt * 32 * 1024 + nt * 64;

  __shared__ float As[32][34];
  __shared__ float Bs[32][68];

  const int tm = tid >> 4;
  const int tn = tid & 15;
  float acc0[4] = {0, 0, 0, 0}, acc1[4] = {0, 0, 0, 0};

  for (int k0 = 0; k0 < 256; k0 += 32) {
    {
      const int m = tid >> 3, kq = tid & 7;
      const int kg = kc * 256 + k0 + kq * 4;
      const float* Ab = Apart + (size_t)(mt * 32 + m) * 1024 + kg;
      float4 v = *reinterpret_cast<const float4*>(abias + kg);
#pragma unroll
      for (int r = 0; r < 4; ++r) {
        const float4 p = *reinterpret_cast<const float4*>(Ab + (size_t)r * 65536);
        v.x += p.x; v.y += p.y; v.z += p.z; v.w += p.w;
      }
      As[kq * 4 + 0][m] = v.x; As[kq * 4 + 1][m] = v.y;
      As[kq * 4 + 2][m] = v.z; As[kq * 4 + 3][m] = v.w;
    }
#pragma unroll
    for (int r = 0; r < 2; ++r) {
      const int idx = r * 256 + tid;
      const int n = idx >> 3, kq = idx & 7;
      float4 v = *reinterpret_cast<const float4*>(B + (size_t)n * 1024 + k0 + kq * 4);
      Bs[kq * 4 + 0][n] = v.x; Bs[kq * 4 + 1][n] = v.y;
      Bs[kq * 4 + 2][n] = v.z; Bs[kq * 4 + 3][n] = v.w;
    }
    __syncthreads();
#pragma unroll
    for (int k = 0; k < 32; ++k) {
      const float a0 = As[k][tm * 2], a1 = As[k][tm * 2 + 1];
      const float4 bb = *reinterpret_cast<const float4*>(&Bs[k][tn * 4]);
      acc0[0] += a0 * bb.x; acc0[1] += a0 * bb.y; acc0[2] += a0 * bb.z; acc0[3] += a0 * bb.w;
      acc1[0] += a1 * bb.x; acc1[1] += a1 * bb.y; acc1[2] += a1 * bb.z; acc1[3] += a1 * bb.w;
    }
    __syncthreads();
  }
  *reinterpret_cast<float4*>(Cp + (size_t)(tm * 2) * 1024 + tn * 4) =
      make_float4(acc0[0], acc0[1], acc0[2], acc0[3]);
  *reinterpret_cast<float4*>(Cp + (size_t)(tm * 2 + 1) * 1024 + tn * 4) =
      make_float4(acc1[0], acc1[1], acc1[2], acc1[3]);
}

// ---------------- reduce 4 split-K partials + bias ----------------
__global__ __launch_bounds__(256) void reduce4_bias(const float* __restrict__ part,
                                                    const float* __restrict__ bias,
                                                    float* __restrict__ out) {
  const int i = blockIdx.x * 256 + threadIdx.x;  // 65536
  out[i] = part[i] + part[i + 65536] + part[i + 131072] + part[i + 196608] + bias[i & 1023];
}

// ---------------- T GEMM: T[s][h][b*16+v][c] = (rot_v q0)_half_s . WkT[c] ----------------
// Rotated-q A-tile computed in-block (per-y/x RoPE of q0); B = wkT (bf16, bias col 1024).
// M=1024 (b,v), N=1152, K=64. Block 128x128, 4 waves of 64x64, MFMA 16x16x32.
__global__ __launch_bounds__(256) void tgemm_rot(
    const unsigned short* __restrict__ wkT, const float* __restrict__ q0p,
    const float* __restrict__ qkv_b, const float2* __restrict__ sc,
    unsigned short* __restrict__ T) {
  const int nt = blockIdx.x;  // 9
  const int mt = blockIdx.y;  // 8
  const int z = blockIdx.z;   // 16
  const int h = z >> 1, s = z & 1;
  const int tid = threadIdx.x;
  const int w = tid >> 6, lane = tid & 63;
  const int wr = w >> 1, wc = w & 1;

  __shared__ __align__(16) char smem[34816];
  char* Ab = smem;                                         // [128 m][128 B]
  char* Bb = smem + 16384;                                 // [128 c][128 B]
  float* q0red = reinterpret_cast<float*>(smem + 32768);   // [8 b][64 d]

  // B stage (gload, pre-swizzled source; 8-slot rows)
#pragma unroll
  for (int i = 0; i < 4; ++i) {
    const int g = w * 4 + i;
    const int row = g * 8 + (lane >> 3);
    const int sl = ((lane & 7) ^ ((row >> 1) & 7)) * 8;
    gload_lds16(wkT + ((size_t)h * 1152 + nt * 128 + row) * 128 + s * 64 + sl, Bb + g * 1024);
  }
  // q0 half reduce (+ q-bias) for this (mt, h, s)
  for (int idx = tid; idx < 512; idx += 256) {
    const int bl = idx >> 6, d = idx & 63;
    const int b = mt * 8 + bl;
    const float* qp = q0p + (size_t)b * 2048 + h * 128 + s * 64 + d;
    q0red[idx] = qkv_b[h * 128 + s * 64 + d] + qp[0] + qp[131072] + qp[262144] + qp[393216];
  }
  __syncthreads();  // q0red visible; B resident (vmcnt drained)

  // A compute: rotated q rows (bf16), swizzled ds_write
  {
    const int r = tid >> 1;             // m-row 0..127
    const int ph = (tid & 1) * 16;      // pair start
    const int v = r & 15;
    const int jrep = (s == 0) ? v * 16 : v;
    const float* qr = q0red + (r >> 4) * 64;
    const int swz = (r >> 1) & 7;
#pragma unroll
    for (int g = 0; g < 4; ++g) {
      unsigned pk[4];
#pragma unroll
      for (int e = 0; e < 4; ++e) {
        const int p = ph + g * 4 + e;
        const float qe = qr[2 * p], qo = qr[2 * p + 1];
        const float2 tt = sc[(s * 32 + p) * 256 + jrep];
        const float ae = qe * tt.y + qo * tt.x;
        const float ao = qo * tt.y - qe * tt.x;
        pk[e] = (unsigned)f2bf(ae) | ((unsigned)f2bf(ao) << 16);
      }
      const int slot = ((ph >> 2) + g) ^ swz;
      *reinterpret_cast<uint4*>(Ab + r * 128 + slot * 16) = make_uint4(pk[0], pk[1], pk[2], pk[3]);
    }
  }
  __syncthreads();

  f32x4 acc[4][4] = {};
#pragma unroll
  for (int kk = 0; kk < 2; ++kk) {
    bf16x8 af[4], bf[4];
#pragma unroll
    for (int mi = 0; mi < 4; ++mi) {
      const int row = wr * 64 + mi * 16 + (lane & 15);
      const int slot = (kk * 4 + (lane >> 4)) ^ ((row >> 1) & 7);
      af[mi] = *reinterpret_cast<const bf16x8*>(Ab + row * 128 + (slot << 4));
    }
#pragma unroll
    for (int ni = 0; ni < 4; ++ni) {
      const int row = wc * 64 + ni * 16 + (lane & 15);
      const int slot = (kk * 4 + (lane >> 4)) ^ ((row >> 1) & 7);
      bf[ni] = *reinterpret_cast<const bf16x8*>(Bb + row * 128 + (slot << 4));
    }
#pragma unroll
    for (int mi = 0; mi < 4; ++mi)
#pragma unroll
      for (int ni = 0; ni < 4; ++ni)
        acc[mi][ni] = __builtin_amdgcn_mfma_f32_16x16x32_bf16(af[mi], bf[ni], acc[mi][ni], 0, 0, 0);
  }

  // C write (bf16): C/D map col=lane&15, row=(lane>>4)*4+rr
  unsigned short* Tz = T + (size_t)(s * 8 + h) * 1024 * 1152;
#pragma unroll
  for (int mi = 0; mi < 4; ++mi)
#pragma unroll
    for (int ni = 0; ni < 4; ++ni) {
      const int col = nt * 128 + wc * 64 + ni * 16 + (lane & 15);
#pragma unroll
      for (int rr = 0; rr < 4; ++rr) {
        const int row = mt * 128 + wr * 64 + mi * 16 + (lane >> 4) * 4 + rr;
        Tz[(size_t)row * 1152 + col] = f2bf(acc[mi][ni][rr]);
      }
    }
}

// ---------------- gathered dots + fused softmax ----------------
// Block (b,h): S[j=(y,x)] = (ty[y]+tx[x]).x_j + ty_bias[y] + tx_bias[x];
// token-0 = q0.k0 from partials; softmax over 257 -> attn.
__global__ __launch_bounds__(256) void dots_softmax(
    const unsigned short* __restrict__ T, const unsigned short* __restrict__ xt,
    const float* __restrict__ q0p, const float* __restrict__ qkv_b,
    float* __restrict__ attn) {
  const int l = blockIdx.x;  // 512; same-b blocks share an XCD slot
  const int b = ((l >> 6) << 3) | (l & 7);
  const int h = (l >> 3) & 7;
  const int tid = threadIdx.x;
  const int w = tid >> 6, lane = tid & 63;

  __shared__ __align__(16) float txf[16][1032];  // Tx half in f32 (+pad)
  __shared__ float txb[16];
  __shared__ float q0_lds[128], k0_lds[128];
  __shared__ float Ssc[257];
  __shared__ float ps[2], r4a[4], r4b[4];

  const unsigned short* Ty = T + (size_t)h * 1024 * 1152;
  const unsigned short* Tx = T + (size_t)(8 + h) * 1024 * 1152;

  // stage Tx -> f32 LDS
  {
    const int xx = tid >> 4, cb = (tid & 15) * 64;
    const unsigned short* src = Tx + (size_t)(b * 16 + xx) * 1152 + cb;
#pragma unroll
    for (int i = 0; i < 16; ++i) {
      const ushort4 v = *reinterpret_cast<const ushort4*>(src + i * 4);
      float4 f = make_float4(bf2f(v.x), bf2f(v.y), bf2f(v.z), bf2f(v.w));
      *reinterpret_cast<float4*>(&txf[xx][cb + i * 4]) = f;
    }
  }
  if (tid < 16) txb[tid] = bf2f(Tx[(size_t)(b * 16 + tid) * 1152 + 1024]);
  if (tid < 128) {
    const float* qp = q0p + (size_t)b * 2048 + h * 128 + tid;
    q0_lds[tid] = qkv_b[h * 128 + tid] + qp[0] + qp[131072] + qp[262144] + qp[393216];
    const float* kp = qp + 1024;
    k0_lds[tid] = qkv_b[1024 + h * 128 + tid] + kp[0] + kp[131072] + kp[262144] + kp[393216];
  }
  __syncthreads();
  if (tid < 128) {
    float pr = q0_lds[tid] * k0_lds[tid];
    pr = wave_reduce_sum(pr);
    if (lane == 0) ps[w] = pr;
  }

  // per-wave y loop (4 y's per wave)
  for (int yi = 0; yi < 4; ++yi) {
    const int y = w + yi * 4;
    const unsigned short* tyr = Ty + (size_t)(b * 16 + y) * 1152;
    float tyf[16];
#pragma unroll
    for (int k = 0; k < 4; ++k) {
      const ushort4 v = *reinterpret_cast<const ushort4*>(tyr + lane * 4 + 256 * k);
      tyf[k * 4 + 0] = bf2f(v.x); tyf[k * 4 + 1] = bf2f(v.y);
      tyf[k * 4 + 2] = bf2f(v.z); tyf[k * 4 + 3] = bf2f(v.w);
    }
    const float tyb = bf2f(tyr[1024]);
    const unsigned short* xb = xt + (size_t)b * 262144 + (size_t)y * 16384;
    ushort4 xv[4], nx[4];
#pragma unroll
    for (int k = 0; k < 4; ++k)
      xv[k] = *reinterpret_cast<const ushort4*>(xb + lane * 4 + 256 * k);
    for (int xx = 0; xx < 16; ++xx) {
      if (xx < 15) {
#pragma unroll
        for (int k = 0; k < 4; ++k)
          nx[k] = *reinterpret_cast<const ushort4*>(xb + (xx + 1) * 1024 + lane * 4 + 256 * k);
      }
      float a = 0.0f;
#pragma unroll
      for (int k = 0; k < 4; ++k) {
        const float4 tx4 = *reinterpret_cast<const float4*>(&txf[xx][lane * 4 + 256 * k]);
        a += (tyf[k * 4 + 0] + tx4.x) * bf2f(xv[k].x);
        a += (tyf[k * 4 + 1] + tx4.y) * bf2f(xv[k].y);
        a += (tyf[k * 4 + 2] + tx4.z) * bf2f(xv[k].z);
        a += (tyf[k * 4 + 3] + tx4.w) * bf2f(xv[k].w);
      }
      a = wave_reduce_sum(a);
      if (lane == 0) Ssc[1 + y * 16 + xx] = a + tyb + txb[xx];
      if (xx < 15) {
#pragma unroll
        for (int k = 0; k < 4; ++k) xv[k] = nx[k];
      }
    }
  }
  __syncthreads();
  if (tid == 0) Ssc[0] = ps[0] + ps[1];
  __syncthreads();

  // softmax over 257 tokens (thread tid = token tid; tid 0 also token 256)
  const float scale = 0.08838834764831845f;
  const float va = Ssc[tid] * scale;
  const float vb = (tid == 0) ? Ssc[256] * scale : -3.0e38f;
  float mx = fmaxf(va, vb);
#pragma unroll
  for (int off = 32; off; off >>= 1) mx = fmaxf(mx, __shfl_xor(mx, off));
  if (lane == 0) r4a[w] = mx;
  __syncthreads();
  const float gmx = fmaxf(fmaxf(r4a[0], r4a[1]), fmaxf(r4a[2], r4a[3]));
  const float ea = expf(va - gmx);
  const float eb = (tid == 0) ? expf(vb - gmx) : 0.0f;
  float sm = ea + eb;
#pragma unroll
  for (int off = 32; off; off >>= 1) sm += __shfl_xor(sm, off);
  if (lane == 0) r4b[w] = sm;
  __syncthreads();
  const float inv = 1.0f / (r4b[0] + r4b[1] + r4b[2] + r4b[3]);
  float* ab = attn + (size_t)(b * 8 + h) * 257;
  ab[tid] = ea * inv;
  if (tid == 0) ab[256] = eb * inv;
}

// ---------------- u[b,h,c] = sum_j attn[b,h,j] * t_j[c]  (reads bf16 x_t) ----------------
__global__ __launch_bounds__(256) void u_accum_kernel(const unsigned short* __restrict__ xt,
                                                      const float* __restrict__ t_mean,
                                                      const float* __restrict__ attn,
                                                      float* __restrict__ u) {
  const int ct = blockIdx.x;  // 8 tiles of 128 channels
  const int b = blockIdx.y;
  const int tid = threadIdx.x;
  __shared__ float aw[2056];
  __shared__ float red[8192];  // [8 q][1024]
  for (int i = tid; i < 2056; i += 256) aw[i] = attn[(size_t)(b * 8 + (i & 7)) * 257 + (i >> 3)];
  __syncthreads();
  const int cl = tid & 31, q = tid >> 5;
  const int c = ct * 128 + cl * 4;
  const unsigned short* xr = xt + (size_t)b * 262144 + c;
  float acc[8][4] = {};
  for (int p = q * 32; p < q * 32 + 32; ++p) {
    const ushort4 v = *reinterpret_cast<const ushort4*>(xr + (size_t)p * 1024);
    const float xs[4] = {bf2f(v.x), bf2f(v.y), bf2f(v.z), bf2f(v.w)};
    const float* w8 = &aw[(p + 1) * 8];
#pragma unroll
    for (int hh = 0; hh < 8; ++hh)
#pragma unroll
      for (int e = 0; e < 4; ++e) acc[hh][e] += w8[hh] * xs[e];
  }
#pragma unroll
  for (int hh = 0; hh < 8; ++hh)
#pragma unroll
    for (int e = 0; e < 4; ++e) red[q * 1024 + (cl * 8 + hh) * 4 + e] = acc[hh][e];
  __syncthreads();
#pragma unroll
  for (int r = 0; r < 4; ++r) {
    const int o = tid * 4 + r;  // 0..1023
    const int cl2 = o >> 5, hh = (o >> 2) & 7, e = o & 3;
    float s = 0.0f;
#pragma unroll
    for (int qq = 0; qq < 8; ++qq) s += red[qq * 1024 + o];
    const int cc = ct * 128 + cl2 * 4 + e;
    s += aw[hh] * t_mean[b * 1024 + cc];
    u[(size_t)(b * 8 + hh) * 1024 + cc] = s;
  }
}

// ---------------- host side ----------------
extern "C" void kernel_launch(void* const* d_in, const int* in_sizes, int n_in,
                              void* d_out, int out_size, void* d_ws, size_t ws_size,
                              hipStream_t stream) {
  const float* x = (const float*)d_in[0];
  const float* qkv_w = (const float*)d_in[1];
  const float* qkv_b = (const float*)d_in[2];
  const float* proj_w = (const float*)d_in[3];
  const float* proj_b = (const float*)d_in[4];
  float* out = (float*)d_out;

  float* ws = (float*)d_ws;
  float* t_mean = ws;                                        // 65536
  float* q0k0_part = ws + 65536;                             // 524288
  float* attn = ws + 589824;                                 // 131584
  float* u = ws + 721408;                                    // 524288
  float* out0_part = ws + 1245696;                           // 262144
  float* out_part = ws + 1507840;                            // 262144
  float2* sc = (float2*)(ws + 1769984);                      // 16384 float2
  unsigned short* wkT = (unsigned short*)(ws + 1802752);     // 8*1152*128 u16
  unsigned short* T = (unsigned short*)(ws + 2392576);       // 2*8*1024*1152 u16
  unsigned short* x_t = (unsigned short*)(ws + 11829760);    // 16.78M u16

  // 1. fused prep: x->x_t+mean (1024) | wkT transpose (256) | wkT bias rows (8) | sc (64)
  prep_kernel<<<1352, 256, 0, stream>>>(x, qkv_w, qkv_b, x_t, t_mean, wkT, sc);

  // 2. q0k0 partials: t_mean @ qkv_w[0:2048].T  (M=64,N=2048,K=4x256)
  gemm_splitk<<<dim3(32, 2, 4), 256, 0, stream>>>(t_mean, 1024, 0, qkv_w, 1024, 0,
                                                  q0k0_part, 2048, 0, 131072, 4);

  // 3. T = rotated-q0 @ WkT (factorized RoPE; M=1024,N=1152,K=64, per h,half)
  tgemm_rot<<<dim3(9, 8, 16), 256, 0, stream>>>(wkT, q0k0_part, qkv_b, sc, T);

  // 4. gathered dots + fused softmax -> attn
  dots_softmax<<<512, 256, 0, stream>>>(T, x_t, q0k0_part, qkv_b, attn);

  // 5. u = attn^T * t (bf16 x_t)
  u_accum_kernel<<<dim3(8, 64), 256, 0, stream>>>(x_t, t_mean, attn, u);

  // 6. out0 partials: per-head Wv_h . u  (Z=8, K=4x256)
  gemm_splitk<<<dim3(2, 2, 32), 256, 0, stream>>>(u, 8192, 1024,
                                                  qkv_w + (size_t)2048 * 1024, 1024, 131072,
                                                  out0_part, 1024, 128, 65536, 4);

  // 7. proj partials, A = reduce4(out0_part)+bias_v inline
  gemm_proj_splitk<<<dim3(16, 2, 4), 256, 0, stream>>>(out0_part, qkv_b + 2048, proj_w, out_part);

  // 8. final reduce + proj bias
  reduce4_bias<<<256, 256, 0, stream>>>(out_part, proj_b, out);
}

// Round 9
// 107.105 us; speedup vs baseline: 1.4955x; 1.4955x over previous
//
#include <hip/hip_runtime.h>
#include <math.h>

#define PI_F 3.14159265358979323846f
#define KSTEP 0.21959209425992272f /* (log2(224)-1)/31 */

using bf16x8 = __attribute__((ext_vector_type(8))) short;
using f32x4 = __attribute__((ext_vector_type(4))) float;
using u16x8 = __attribute__((ext_vector_type(8))) unsigned short;

static __device__ __forceinline__ float wave_reduce_sum(float v) {
#pragma unroll
  for (int off = 32; off; off >>= 1) v += __shfl_down(v, off);
  return v;
}

static __device__ __forceinline__ unsigned short f2bf(float f) {
  unsigned u = __float_as_uint(f);
  return (unsigned short)((u + 0x7fffu + ((u >> 16) & 1u)) >> 16);
}

static __device__ __forceinline__ float bf2f(unsigned short s) {
  return __uint_as_float(((unsigned)s) << 16);
}

static __device__ __forceinline__ void gload_lds16(const void* g, void* l) {
  __builtin_amdgcn_global_load_lds((const __attribute__((address_space(1))) unsigned int*)g,
                                   (__attribute__((address_space(3))) unsigned int*)l, 16, 0, 0);
}

// ---- fused prep: x->bf16 x_t + t_mean | wkT (transposed Wk + bias row) | sc table ----
__global__ __launch_bounds__(256) void prep_kernel(const float* __restrict__ x,
                                                   const float* __restrict__ qkv_w,
                                                   const float* __restrict__ qkv_b,
                                                   unsigned short* __restrict__ xt,
                                                   float* __restrict__ t_mean,
                                                   unsigned short* __restrict__ wkT,
                                                   float2* __restrict__ sc) {
  const int bid = blockIdx.x;
  const int t = threadIdx.x;
  __shared__ float tile[64 * 33];
  __shared__ float tl2[64 * 65];
  if (bid < 1024) {
    const int ct = bid & 15, b = bid >> 4;
    const int cl = t >> 2, pq = (t & 3) * 8;  // read role
    const int pl = t >> 3, cq = (t & 7) * 8;  // write role
    float sum = 0.0f;
    const float* xrow = x + ((size_t)(b * 1024 + ct * 64 + cl) * 256) + pq;
    unsigned short* xtb = xt + (size_t)b * 262144 + ct * 64;
    for (int pt = 0; pt < 8; ++pt) {
      const float4 v0 = *reinterpret_cast<const float4*>(xrow + pt * 32);
      const float4 v1 = *reinterpret_cast<const float4*>(xrow + pt * 32 + 4);
      tile[cl * 33 + pq + 0] = v0.x; tile[cl * 33 + pq + 1] = v0.y;
      tile[cl * 33 + pq + 2] = v0.z; tile[cl * 33 + pq + 3] = v0.w;
      tile[cl * 33 + pq + 4] = v1.x; tile[cl * 33 + pq + 5] = v1.y;
      tile[cl * 33 + pq + 6] = v1.z; tile[cl * 33 + pq + 7] = v1.w;
      sum += (v0.x + v0.y) + (v0.z + v0.w) + (v1.x + v1.y) + (v1.z + v1.w);
      __syncthreads();
      u16x8 o;
#pragma unroll
      for (int e = 0; e < 8; ++e) o[e] = f2bf(tile[(cq + e) * 33 + pl]);
      *reinterpret_cast<u16x8*>(xtb + (size_t)(pt * 32 + pl) * 1024 + cq) = o;
      __syncthreads();
    }
    sum += __shfl_xor(sum, 1);
    sum += __shfl_xor(sum, 2);
    if ((t & 3) == 0) t_mean[b * 1024 + ct * 64 + cl] = sum * (1.0f / 256.0f);
  } else if (bid < 1280) {
    // wkT[h][c][d] transpose tiles: bf16, c rows, d contiguous
    const int bb = bid - 1024;
    const int h = bb >> 5, t5 = bb & 31;
    const int dt = t5 >> 4, ct = t5 & 15;
    {
      const int dl = t >> 2, cq = (t & 3) * 16;
      const float* src = qkv_w + (size_t)(1024 + h * 128 + dt * 64 + dl) * 1024 + ct * 64 + cq;
#pragma unroll
      for (int i = 0; i < 4; ++i) {
        const float4 v = *reinterpret_cast<const float4*>(src + i * 4);
        tl2[dl * 65 + cq + i * 4 + 0] = v.x; tl2[dl * 65 + cq + i * 4 + 1] = v.y;
        tl2[dl * 65 + cq + i * 4 + 2] = v.z; tl2[dl * 65 + cq + i * 4 + 3] = v.w;
      }
    }
    __syncthreads();
    {
      const int cl = t >> 2, dq = (t & 3) * 16;
      unsigned short* dst = wkT + (size_t)(h * 1152 + ct * 64 + cl) * 128 + dt * 64 + dq;
      u16x8 o0, o1;
#pragma unroll
      for (int e = 0; e < 8; ++e) {
        o0[e] = f2bf(tl2[(dq + e) * 65 + cl]);
        o1[e] = f2bf(tl2[(dq + 8 + e) * 65 + cl]);
      }
      *reinterpret_cast<u16x8*>(dst) = o0;
      *reinterpret_cast<u16x8*>(dst + 8) = o1;
    }
  } else if (bid < 1288) {
    // wkT rows 1024..1151: row 1024 = k-bias, rest zero
    const int h = bid - 1280;
    for (int idx = t; idx < 16384; idx += 256) {
      const int row = 1024 + (idx >> 7), d = idx & 127;
      unsigned short v = 0;
      if (row == 1024) v = f2bf(qkv_b[1024 + h * 128 + d]);
      wkT[(size_t)(h * 1152 + row) * 128 + d] = v;
    }
  } else {
    const int idx = (bid - 1288) * 256 + t;  // 16384
    const int m = idx >> 8, j = idx & 255;
    const float band = exp2f((float)(m & 31) * KSTEP) * PI_F;
    const float coord = (m < 32) ? (-1.0f + (2.0f / 15.0f) * (float)(j >> 4))
                                 : (-1.0f + (2.0f / 15.0f) * (float)(j & 15));
    float sn, cs;
    sincosf(coord * band, &sn, &cs);
    sc[idx] = make_float2(sn, cs);
  }
}

// ---------------- split-K skinny GEMM: Cp[kc] = A * B^T (K-chunk = 256) ----------------
__global__ __launch_bounds__(256) void gemm_splitk(
    const float* __restrict__ A, int lda, int aStrideZ,
    const float* __restrict__ B, int ldb, int bStrideZ,
    float* __restrict__ Cp, int ldc, int cStrideZ, int cStrideKc, int KC) {
  const int nt = blockIdx.x, mt = blockIdx.y;
  const int z = blockIdx.z / KC, kc = blockIdx.z % KC;
  const int tid = threadIdx.x;
  A += (size_t)z * aStrideZ + (size_t)mt * 32 * lda + kc * 256;
  B += (size_t)z * bStrideZ + (size_t)nt * 64 * ldb + kc * 256;
  Cp += (size_t)kc * cStrideKc + (size_t)z * cStrideZ + (size_t)mt * 32 * ldc + nt * 64;

  __shared__ float As[32][34];
  __shared__ float Bs[32][68];

  const int tm = tid >> 4;
  const int tn = tid & 15;
  float acc0[4] = {0, 0, 0, 0}, acc1[4] = {0, 0, 0, 0};

  for (int k0 = 0; k0 < 256; k0 += 32) {
    {
      const int m = tid >> 3, kq = tid & 7;
      float4 v = *reinterpret_cast<const float4*>(A + (size_t)m * lda + k0 + kq * 4);
      As[kq * 4 + 0][m] = v.x; As[kq * 4 + 1][m] = v.y;
      As[kq * 4 + 2][m] = v.z; As[kq * 4 + 3][m] = v.w;
    }
#pragma unroll
    for (int r = 0; r < 2; ++r) {
      const int idx = r * 256 + tid;
      const int n = idx >> 3, kq = idx & 7;
      float4 v = *reinterpret_cast<const float4*>(B + (size_t)n * ldb + k0 + kq * 4);
      Bs[kq * 4 + 0][n] = v.x; Bs[kq * 4 + 1][n] = v.y;
      Bs[kq * 4 + 2][n] = v.z; Bs[kq * 4 + 3][n] = v.w;
    }
    __syncthreads();
#pragma unroll
    for (int k = 0; k < 32; ++k) {
      const float a0 = As[k][tm * 2], a1 = As[k][tm * 2 + 1];
      const float4 bb = *reinterpret_cast<const float4*>(&Bs[k][tn * 4]);
      acc0[0] += a0 * bb.x; acc0[1] += a0 * bb.y; acc0[2] += a0 * bb.z; acc0[3] += a0 * bb.w;
      acc1[0] += a1 * bb.x; acc1[1] += a1 * bb.y; acc1[2] += a1 * bb.z; acc1[3] += a1 * bb.w;
    }
    __syncthreads();
  }
  *reinterpret_cast<float4*>(Cp + (size_t)(tm * 2) * ldc + tn * 4) =
      make_float4(acc0[0], acc0[1], acc0[2], acc0[3]);
  *reinterpret_cast<float4*>(Cp + (size_t)(tm * 2 + 1) * ldc + tn * 4) =
      make_float4(acc1[0], acc1[1], acc1[2], acc1[3]);
}

// ---------------- proj GEMM with inline 4-partial A reduce + Wv-bias ----------------
__global__ __launch_bounds__(256) void gemm_proj_splitk(
    const float* __restrict__ Apart, const float* __restrict__ abias,
    const float* __restrict__ B, float* __restrict__ Cp) {
  const int nt = blockIdx.x, mt = blockIdx.y, kc = blockIdx.z;
  const int tid = threadIdx.x;
  B += (size_t)nt * 64 * 1024 + kc * 256;
  Cp += (size_t)kc * 65536 + (size_t)mt * 32 * 1024 + nt * 64;

  __shared__ float As[32][34];
  __shared__ float Bs[32][68];

  const int tm = tid >> 4;
  const int tn = tid & 15;
  float acc0[4] = {0, 0, 0, 0}, acc1[4] = {0, 0, 0, 0};

  for (int k0 = 0; k0 < 256; k0 += 32) {
    {
      const int m = tid >> 3, kq = tid & 7;
      const int kg = kc * 256 + k0 + kq * 4;
      const float* Ab = Apart + (size_t)(mt * 32 + m) * 1024 + kg;
      float4 v = *reinterpret_cast<const float4*>(abias + kg);
#pragma unroll
      for (int r = 0; r < 4; ++r) {
        const float4 p = *reinterpret_cast<const float4*>(Ab + (size_t)r * 65536);
        v.x += p.x; v.y += p.y; v.z += p.z; v.w += p.w;
      }
      As[kq * 4 + 0][m] = v.x; As[kq * 4 + 1][m] = v.y;
      As[kq * 4 + 2][m] = v.z; As[kq * 4 + 3][m] = v.w;
    }
#pragma unroll
    for (int r = 0; r < 2; ++r) {
      const int idx = r * 256 + tid;
      const int n = idx >> 3, kq = idx & 7;
      float4 v = *reinterpret_cast<const float4*>(B + (size_t)n * 1024 + k0 + kq * 4);
      Bs[kq * 4 + 0][n] = v.x; Bs[kq * 4 + 1][n] = v.y;
      Bs[kq * 4 + 2][n] = v.z; Bs[kq * 4 + 3][n] = v.w;
    }
    __syncthreads();
#pragma unroll
    for (int k = 0; k < 32; ++k) {
      const float a0 = As[k][tm * 2], a1 = As[k][tm * 2 + 1];
      const float4 bb = *reinterpret_cast<const float4*>(&Bs[k][tn * 4]);
      acc0[0] += a0 * bb.x; acc0[1] += a0 * bb.y; acc0[2] += a0 * bb.z; acc0[3] += a0 * bb.w;
      acc1[0] += a1 * bb.x; acc1[1] += a1 * bb.y; acc1[2] += a1 * bb.z; acc1[3] += a1 * bb.w;
    }
    __syncthreads();
  }
  *reinterpret_cast<float4*>(Cp + (size_t)(tm * 2) * 1024 + tn * 4) =
      make_float4(acc0[0], acc0[1], acc0[2], acc0[3]);
  *reinterpret_cast<float4*>(Cp + (size_t)(tm * 2 + 1) * 1024 + tn * 4) =
      make_float4(acc1[0], acc1[1], acc1[2], acc1[3]);
}

// ---------------- reduce 4 split-K partials + bias ----------------
__global__ __launch_bounds__(256) void reduce4_bias(const float* __restrict__ part,
                                                    const float* __restrict__ bias,
                                                    float* __restrict__ out) {
  const int i = blockIdx.x * 256 + threadIdx.x;  // 65536
  out[i] = part[i] + part[i + 65536] + part[i + 131072] + part[i + 196608] + bias[i & 1023];
}

// ---------------- T GEMM: T[s][h][b*16+v][c] = (rot_v q0)_half_s . WkT[c] ----------------
__global__ __launch_bounds__(256) void tgemm_rot(
    const unsigned short* __restrict__ wkT, const float* __restrict__ q0p,
    const float* __restrict__ qkv_b, const float2* __restrict__ sc,
    unsigned short* __restrict__ T) {
  const int nt = blockIdx.x;  // 9
  const int mt = blockIdx.y;  // 8
  const int z = blockIdx.z;   // 16
  const int h = z >> 1, s = z & 1;
  const int tid = threadIdx.x;
  const int w = tid >> 6, lane = tid & 63;
  const int wr = w >> 1, wc = w & 1;

  __shared__ __align__(16) char smem[34816];
  char* Ab = smem;                                         // [128 m][128 B]
  char* Bb = smem + 16384;                                 // [128 c][128 B]
  float* q0red = reinterpret_cast<float*>(smem + 32768);   // [8 b][64 d]

  // B stage (gload, pre-swizzled source; 8-slot rows)
#pragma unroll
  for (int i = 0; i < 4; ++i) {
    const int g = w * 4 + i;
    const int row = g * 8 + (lane >> 3);
    const int sl = ((lane & 7) ^ ((row >> 1) & 7)) * 8;
    gload_lds16(wkT + ((size_t)h * 1152 + nt * 128 + row) * 128 + s * 64 + sl, Bb + g * 1024);
  }
  // q0 half reduce (+ q-bias) for this (mt, h, s)
  for (int idx = tid; idx < 512; idx += 256) {
    const int bl = idx >> 6, d = idx & 63;
    const int b = mt * 8 + bl;
    const float* qp = q0p + (size_t)b * 2048 + h * 128 + s * 64 + d;
    q0red[idx] = qkv_b[h * 128 + s * 64 + d] + qp[0] + qp[131072] + qp[262144] + qp[393216];
  }
  __syncthreads();  // q0red visible; B resident (vmcnt drained)

  // A compute: rotated q rows (bf16), swizzled ds_write
  {
    const int r = tid >> 1;             // m-row 0..127
    const int ph = (tid & 1) * 16;      // pair start
    const int v = r & 15;
    const int jrep = (s == 0) ? v * 16 : v;
    const float* qr = q0red + (r >> 4) * 64;
    const int swz = (r >> 1) & 7;
#pragma unroll
    for (int g = 0; g < 4; ++g) {
      unsigned pk[4];
#pragma unroll
      for (int e = 0; e < 4; ++e) {
        const int p = ph + g * 4 + e;
        const float qe = qr[2 * p], qo = qr[2 * p + 1];
        const float2 tt = sc[(s * 32 + p) * 256 + jrep];
        const float ae = qe * tt.y + qo * tt.x;
        const float ao = qo * tt.y - qe * tt.x;
        pk[e] = (unsigned)f2bf(ae) | ((unsigned)f2bf(ao) << 16);
      }
      const int slot = ((ph >> 2) + g) ^ swz;
      *reinterpret_cast<uint4*>(Ab + r * 128 + slot * 16) = make_uint4(pk[0], pk[1], pk[2], pk[3]);
    }
  }
  __syncthreads();

  f32x4 acc[4][4] = {};
#pragma unroll
  for (int kk = 0; kk < 2; ++kk) {
    bf16x8 af[4], bf[4];
#pragma unroll
    for (int mi = 0; mi < 4; ++mi) {
      const int row = wr * 64 + mi * 16 + (lane & 15);
      const int slot = (kk * 4 + (lane >> 4)) ^ ((row >> 1) & 7);
      af[mi] = *reinterpret_cast<const bf16x8*>(Ab + row * 128 + (slot << 4));
    }
#pragma unroll
    for (int ni = 0; ni < 4; ++ni) {
      const int row = wc * 64 + ni * 16 + (lane & 15);
      const int slot = (kk * 4 + (lane >> 4)) ^ ((row >> 1) & 7);
      bf[ni] = *reinterpret_cast<const bf16x8*>(Bb + row * 128 + (slot << 4));
    }
#pragma unroll
    for (int mi = 0; mi < 4; ++mi)
#pragma unroll
      for (int ni = 0; ni < 4; ++ni)
        acc[mi][ni] = __builtin_amdgcn_mfma_f32_16x16x32_bf16(af[mi], bf[ni], acc[mi][ni], 0, 0, 0);
  }

  // C write (bf16): C/D map col=lane&15, row=(lane>>4)*4+rr
  unsigned short* Tz = T + (size_t)(s * 8 + h) * 1024 * 1152;
#pragma unroll
  for (int mi = 0; mi < 4; ++mi)
#pragma unroll
    for (int ni = 0; ni < 4; ++ni) {
      const int col = nt * 128 + wc * 64 + ni * 16 + (lane & 15);
#pragma unroll
      for (int rr = 0; rr < 4; ++rr) {
        const int row = mt * 128 + wr * 64 + mi * 16 + (lane >> 4) * 4 + rr;
        Tz[(size_t)row * 1152 + col] = f2bf(acc[mi][ni][rr]);
      }
    }
}

// ---------------- MFMA scores + fused softmax + u ----------------
// Block (b, ht=head-pair): P = X_b(256j x 1024c) @ T_b^T(64n x 1024c) via MFMA;
// S[j,h] = P[j, h*32+y_j] + P[j, h*32+16+x_j] + biases; softmax(257) -> attn (LDS);
// u[h][c] = attn @ [t_mean; X_b]. 3-buf pipeline, counted vmcnt(10), 0-conflict swizzle.
__global__ __launch_bounds__(256, 2) void scores_u(
    const unsigned short* __restrict__ Tg, const unsigned short* __restrict__ xt,
    const float* __restrict__ q0p, const float* __restrict__ qkv_b,
    const float* __restrict__ t_mean, float* __restrict__ u) {
  const int l = blockIdx.x;  // 256; same-b blocks share an XCD (l&7 preserved)
  const int b = ((l >> 5) << 3) | (l & 7);
  const int ht = (l >> 3) & 3;  // head pair: heads ht*2, ht*2+1
  const int tid = threadIdx.x;
  const int w = tid >> 6, lane = tid & 63;

  __shared__ __align__(16) char smem[61440];  // 3 bufs x (A 16KB + B 4KB)

  const unsigned short* xtb = xt + (size_t)b * 262144;

  // Stage one BK=32 tile. A: 256 j-rows (wave w stages rows w*64..+64, 4 gloads).
  // B: 64 T-rows (wave w stages rows w*16..+16, 1 gload). 5 gloads/wave/stage.
#define STAGE(buf, c0)                                                          \
  {                                                                             \
    char* Ab_ = smem + (buf)*20480;                                             \
    char* Bb_ = Ab_ + 16384;                                                    \
    _Pragma("unroll") for (int i = 0; i < 4; ++i) {                             \
      const int row_ = w * 64 + i * 16 + (lane >> 2);                           \
      const int sl_ = ((lane & 3) ^ ((row_ >> 1) & 3)) * 8;                     \
      gload_lds16(xtb + (size_t)row_ * 1024 + (c0) + sl_,                       \
                  Ab_ + (w * 4 + i) * 1024);                                    \
    }                                                                           \
    {                                                                           \
      const int n_ = w * 16 + (lane >> 2);                                      \
      const int h_ = ht * 2 + (n_ >> 5), s_ = (n_ >> 4) & 1, v_ = n_ & 15;      \
      const size_t rowT_ = ((size_t)(s_ * 8 + h_) * 1024 + b * 16 + v_) * 1152; \
      const int sl_ = ((lane & 3) ^ ((n_ >> 1) & 3)) * 8;                       \
      gload_lds16(Tg + rowT_ + (c0) + sl_, Bb_ + w * 1024);                     \
    }                                                                           \
  }

  STAGE(0, 0);
  STAGE(1, 32);
  f32x4 acc[4][4] = {};
  int cur = 0, nxt = 2;
  for (int t = 0; t < 32; ++t) {
    {  // stage tile t+2 (clamped tail keeps vmcnt timeline uniform)
      const int src = (t + 2 > 31) ? 31 : (t + 2);
      STAGE(nxt, src * 32);
    }
    asm volatile("s_waitcnt vmcnt(10)" ::: "memory");  // tile t resident; 2 in flight
    __builtin_amdgcn_s_barrier();
    const char* Ab = smem + cur * 20480;
    const char* Bb = Ab + 16384;
    bf16x8 af[4], bfr[4];
#pragma unroll
    for (int mi = 0; mi < 4; ++mi) {
      const int row = w * 64 + mi * 16 + (lane & 15);
      af[mi] = *reinterpret_cast<const bf16x8*>(
          Ab + row * 64 + ((((lane >> 4) ^ ((row >> 1) & 3))) << 4));
    }
#pragma unroll
    for (int ni = 0; ni < 4; ++ni) {
      const int n = ni * 16 + (lane & 15);
      bfr[ni] = *reinterpret_cast<const bf16x8*>(
          Bb + n * 64 + ((((lane >> 4) ^ ((n >> 1) & 3))) << 4));
    }
    __builtin_amdgcn_s_setprio(1);
#pragma unroll
    for (int mi = 0; mi < 4; ++mi)
#pragma unroll
      for (int ni = 0; ni < 4; ++ni)
        acc[mi][ni] =
            __builtin_amdgcn_mfma_f32_16x16x32_bf16(af[mi], bfr[ni], acc[mi][ni], 0, 0, 0);
    __builtin_amdgcn_s_setprio(0);
    __builtin_amdgcn_s_barrier();
    asm volatile("" ::: "memory");
    cur = (cur == 2) ? 0 : cur + 1;
    nxt = (nxt == 2) ? 0 : nxt + 1;
  }
#undef STAGE

  asm volatile("s_waitcnt vmcnt(0)" ::: "memory");
  __syncthreads();

  // ---- LDS reuse: epilogue arrays ----
  float* Sp = reinterpret_cast<float*>(smem);   // [256 j][2 h][2 s]
  float* bias = Sp + 1024;                      // [2 h][2 s][16 v]
  float* q0l = bias + 64;                       // [256] (2 heads x 128)
  float* k0l = q0l + 256;                       // [256]
  float* ps = k0l + 256;                        // [4]
  float* smax = ps + 4;                         // [8]
  float* ssum = smax + 8;                       // [8]
  float* attnl = ssum + 8;                      // [2][257]
  float* upart = reinterpret_cast<float*>(smem + 16384);  // [4 w][2 h][1024 c]

  // diagonal extraction: each (j, h, s) slot has exactly one writer lane
#pragma unroll
  for (int mi = 0; mi < 4; ++mi)
#pragma unroll
    for (int ni = 0; ni < 4; ++ni)
#pragma unroll
      for (int rr = 0; rr < 4; ++rr) {
        const int j = w * 64 + mi * 16 + ((lane >> 4) << 2) + rr;
        const int col = ni * 16 + (lane & 15);
        const int s = (col >> 4) & 1;
        const int sel = s ? (j & 15) : (j >> 4);
        if ((col & 15) == sel) Sp[(j * 2 + (col >> 5)) * 2 + s] = acc[mi][ni][rr];
      }
  if (tid < 64) {
    const int h_ = tid >> 5, s_ = (tid >> 4) & 1, v_ = tid & 15;
    bias[tid] =
        bf2f(Tg[((size_t)(s_ * 8 + ht * 2 + h_) * 1024 + b * 16 + v_) * 1152 + 1024]);
  }
  {
    const float* qp = q0p + (size_t)b * 2048 + ht * 256 + tid;
    q0l[tid] = qkv_b[ht * 256 + tid] + qp[0] + qp[131072] + qp[262144] + qp[393216];
    const float* kp = qp + 1024;
    k0l[tid] = qkv_b[1024 + ht * 256 + tid] + kp[0] + kp[131072] + kp[262144] + kp[393216];
  }
  __syncthreads();
  {
    float pr = q0l[tid] * k0l[tid];
    pr = wave_reduce_sum(pr);
    if (lane == 0) ps[w] = pr;  // w 0,1 -> head0; 2,3 -> head1
  }
  __syncthreads();

  // ---- dual-head softmax over 257 tokens (thread tid = token 1+tid; tid0 also token 0)
  const float scale = 0.08838834764831845f;
  const float va0 = scale * (Sp[tid * 4 + 0] + Sp[tid * 4 + 1] + bias[tid >> 4] +
                             bias[16 + (tid & 15)]);
  const float va1 = scale * (Sp[tid * 4 + 2] + Sp[tid * 4 + 3] + bias[32 + (tid >> 4)] +
                             bias[48 + (tid & 15)]);
  float vb0 = -3.0e38f, vb1 = -3.0e38f;
  if (tid == 0) {
    vb0 = scale * (ps[0] + ps[1]);
    vb1 = scale * (ps[2] + ps[3]);
  }
  float m0 = fmaxf(va0, vb0), m1 = fmaxf(va1, vb1);
#pragma unroll
  for (int off = 32; off; off >>= 1) {
    m0 = fmaxf(m0, __shfl_xor(m0, off));
    m1 = fmaxf(m1, __shfl_xor(m1, off));
  }
  if (lane == 0) { smax[w] = m0; smax[4 + w] = m1; }
  __syncthreads();
  const float g0 = fmaxf(fmaxf(smax[0], smax[1]), fmaxf(smax[2], smax[3]));
  const float g1 = fmaxf(fmaxf(smax[4], smax[5]), fmaxf(smax[6], smax[7]));
  const float e0 = expf(va0 - g0), e1 = expf(va1 - g1);
  const float eb0 = (tid == 0) ? expf(vb0 - g0) : 0.0f;
  const float eb1 = (tid == 0) ? expf(vb1 - g1) : 0.0f;
  float s0 = e0 + eb0, s1 = e1 + eb1;
#pragma unroll
  for (int off = 32; off; off >>= 1) {
    s0 += __shfl_xor(s0, off);
    s1 += __shfl_xor(s1, off);
  }
  if (lane == 0) { ssum[w] = s0; ssum[4 + w] = s1; }
  __syncthreads();
  const float inv0 = 1.0f / (ssum[0] + ssum[1] + ssum[2] + ssum[3]);
  const float inv1 = 1.0f / (ssum[4] + ssum[5] + ssum[6] + ssum[7]);
  attnl[1 + tid] = e0 * inv0;
  attnl[257 + 1 + tid] = e1 * inv1;
  if (tid == 0) { attnl[0] = eb0 * inv0; attnl[257] = eb1 * inv1; }
  __syncthreads();

  // ---- u: wave w accumulates its 64 j over all 1024 c (lane owns 16 c)
  {
    float ua0[16] = {}, ua1[16] = {};
    const unsigned short* xr = xtb + (size_t)(w * 64) * 1024 + lane * 16;
    for (int jj = 0; jj < 64; ++jj) {
      const float a0 = attnl[1 + w * 64 + jj];
      const float a1 = attnl[257 + 1 + w * 64 + jj];
      const u16x8 v0 = *reinterpret_cast<const u16x8*>(xr + (size_t)jj * 1024);
      const u16x8 v1 = *reinterpret_cast<const u16x8*>(xr + (size_t)jj * 1024 + 8);
#pragma unroll
      for (int e = 0; e < 8; ++e) {
        const float f0 = bf2f((unsigned short)v0[e]);
        const float f1 = bf2f((unsigned short)v1[e]);
        ua0[e] += a0 * f0; ua0[8 + e] += a0 * f1;
        ua1[e] += a1 * f0; ua1[8 + e] += a1 * f1;
      }
    }
#pragma unroll
    for (int e = 0; e < 16; ++e) {
      upart[(w * 2 + 0) * 1024 + lane * 16 + e] = ua0[e];
      upart[(w * 2 + 1) * 1024 + lane * 16 + e] = ua1[e];
    }
  }
  __syncthreads();
#pragma unroll
  for (int r = 0; r < 8; ++r) {
    const int o = tid * 8 + r;  // 0..2047
    const int h2 = o >> 10, c = o & 1023;
    float s = upart[(0 * 2 + h2) * 1024 + c] + upart[(1 * 2 + h2) * 1024 + c] +
              upart[(2 * 2 + h2) * 1024 + c] + upart[(3 * 2 + h2) * 1024 + c];
    s += attnl[h2 * 257] * t_mean[b * 1024 + c];
    u[((size_t)b * 8 + ht * 2 + h2) * 1024 + c] = s;
  }
}

// ---------------- host side ----------------
extern "C" void kernel_launch(void* const* d_in, const int* in_sizes, int n_in,
                              void* d_out, int out_size, void* d_ws, size_t ws_size,
                              hipStream_t stream) {
  const float* x = (const float*)d_in[0];
  const float* qkv_w = (const float*)d_in[1];
  const float* qkv_b = (const float*)d_in[2];
  const float* proj_w = (const float*)d_in[3];
  const float* proj_b = (const float*)d_in[4];
  float* out = (float*)d_out;

  float* ws = (float*)d_ws;
  float* t_mean = ws;                                       // [0, 65536)
  float* q0k0_part = ws + 65536;                            // [65536, 589824)
  float* u = ws + 589824;                                   // [589824, 1114112)
  float* out0_part = ws + 1114112;                          // [1114112, 1376256)
  float* out_part = ws + 1376256;                           // [1376256, 1638400)
  float2* sc = (float2*)(ws + 1638400);                     // [1638400, 1671168)
  unsigned short* wkT = (unsigned short*)(ws + 1671168);    // 1179648 u16 = [1671168, 2260992)
  unsigned short* T = (unsigned short*)(ws + 2260992);      // 18874368 u16 = [2260992, 11698176)
  unsigned short* x_t = (unsigned short*)(ws + 11698176);   // 16777216 u16 = [11698176, 20086784)

  // 1. fused prep: x->x_t+mean | wkT transpose | wkT bias rows | sc table
  prep_kernel<<<1352, 256, 0, stream>>>(x, qkv_w, qkv_b, x_t, t_mean, wkT, sc);

  // 2. q0k0 partials: t_mean @ qkv_w[0:2048].T  (M=64,N=2048,K=4x256)
  gemm_splitk<<<dim3(32, 2, 4), 256, 0, stream>>>(t_mean, 1024, 0, qkv_w, 1024, 0,
                                                  q0k0_part, 2048, 0, 131072, 4);

  // 3. T = rotated-q0 @ WkT (factorized RoPE; M=1024,N=1152,K=64, per h,half)
  tgemm_rot<<<dim3(9, 8, 16), 256, 0, stream>>>(wkT, q0k0_part, qkv_b, sc, T);

  // 4. MFMA scores + softmax + u  (256 blocks = (b, head-pair))
  scores_u<<<256, 256, 0, stream>>>(T, x_t, q0k0_part, qkv_b, t_mean, u);

  // 5. out0 partials: per-head Wv_h . u  (Z=8, K=4x256)
  gemm_splitk<<<dim3(2, 2, 32), 256, 0, stream>>>(u, 8192, 1024,
                                                  qkv_w + (size_t)2048 * 1024, 1024, 131072,
                                                  out0_part, 1024, 128, 65536, 4);

  // 6. proj partials, A = reduce4(out0_part)+bias_v inline
  gemm_proj_splitk<<<dim3(16, 2, 4), 256, 0, stream>>>(out0_part, qkv_b + 2048, proj_w, out_part);

  // 7. final reduce + proj bias
  reduce4_bias<<<256, 256, 0, stream>>>(out_part, proj_b, out);
}

// Round 10
// 101.877 us; speedup vs baseline: 1.5722x; 1.0513x over previous
//
#include <hip/hip_runtime.h>
#include <math.h>

#define PI_F 3.14159265358979323846f
#define KSTEP 0.21959209425992272f /* (log2(224)-1)/31 */

using bf16x8 = __attribute__((ext_vector_type(8))) short;
using f32x4 = __attribute__((ext_vector_type(4))) float;
using u16x8 = __attribute__((ext_vector_type(8))) unsigned short;

static __device__ __forceinline__ float wave_reduce_sum(float v) {
#pragma unroll
  for (int off = 32; off; off >>= 1) v += __shfl_down(v, off);
  return v;
}

static __device__ __forceinline__ unsigned short f2bf(float f) {
  unsigned u = __float_as_uint(f);
  return (unsigned short)((u + 0x7fffu + ((u >> 16) & 1u)) >> 16);
}

static __device__ __forceinline__ float bf2f(unsigned short s) {
  return __uint_as_float(((unsigned)s) << 16);
}

static __device__ __forceinline__ void gload_lds16(const void* g, void* l) {
  __builtin_amdgcn_global_load_lds((const __attribute__((address_space(1))) unsigned int*)g,
                                   (__attribute__((address_space(3))) unsigned int*)l, 16, 0, 0);
}

// ---- fused prep: x->bf16 x_t + t_mean | wkT (transposed Wk + bias row) | sc table ----
__global__ __launch_bounds__(256) void prep_kernel(const float* __restrict__ x,
                                                   const float* __restrict__ qkv_w,
                                                   const float* __restrict__ qkv_b,
                                                   unsigned short* __restrict__ xt,
                                                   float* __restrict__ t_mean,
                                                   unsigned short* __restrict__ wkT,
                                                   float2* __restrict__ sc) {
  const int bid = blockIdx.x;
  const int t = threadIdx.x;
  __shared__ float tile[64 * 33];
  __shared__ float tl2[64 * 65];
  if (bid < 1024) {
    const int ct = bid & 15, b = bid >> 4;
    const int cl = t >> 2, pq = (t & 3) * 8;  // read role
    const int pl = t >> 3, cq = (t & 7) * 8;  // write role
    float sum = 0.0f;
    const float* xrow = x + ((size_t)(b * 1024 + ct * 64 + cl) * 256) + pq;
    unsigned short* xtb = xt + (size_t)b * 262144 + ct * 64;
    for (int pt = 0; pt < 8; ++pt) {
      const float4 v0 = *reinterpret_cast<const float4*>(xrow + pt * 32);
      const float4 v1 = *reinterpret_cast<const float4*>(xrow + pt * 32 + 4);
      tile[cl * 33 + pq + 0] = v0.x; tile[cl * 33 + pq + 1] = v0.y;
      tile[cl * 33 + pq + 2] = v0.z; tile[cl * 33 + pq + 3] = v0.w;
      tile[cl * 33 + pq + 4] = v1.x; tile[cl * 33 + pq + 5] = v1.y;
      tile[cl * 33 + pq + 6] = v1.z; tile[cl * 33 + pq + 7] = v1.w;
      sum += (v0.x + v0.y) + (v0.z + v0.w) + (v1.x + v1.y) + (v1.z + v1.w);
      __syncthreads();
      u16x8 o;
#pragma unroll
      for (int e = 0; e < 8; ++e) o[e] = f2bf(tile[(cq + e) * 33 + pl]);
      *reinterpret_cast<u16x8*>(xtb + (size_t)(pt * 32 + pl) * 1024 + cq) = o;
      __syncthreads();
    }
    sum += __shfl_xor(sum, 1);
    sum += __shfl_xor(sum, 2);
    if ((t & 3) == 0) t_mean[b * 1024 + ct * 64 + cl] = sum * (1.0f / 256.0f);
  } else if (bid < 1280) {
    // wkT[h][c][d] transpose tiles: bf16, c rows, d contiguous
    const int bb = bid - 1024;
    const int h = bb >> 5, t5 = bb & 31;
    const int dt = t5 >> 4, ct = t5 & 15;
    {
      const int dl = t >> 2, cq = (t & 3) * 16;
      const float* src = qkv_w + (size_t)(1024 + h * 128 + dt * 64 + dl) * 1024 + ct * 64 + cq;
#pragma unroll
      for (int i = 0; i < 4; ++i) {
        const float4 v = *reinterpret_cast<const float4*>(src + i * 4);
        tl2[dl * 65 + cq + i * 4 + 0] = v.x; tl2[dl * 65 + cq + i * 4 + 1] = v.y;
        tl2[dl * 65 + cq + i * 4 + 2] = v.z; tl2[dl * 65 + cq + i * 4 + 3] = v.w;
      }
    }
    __syncthreads();
    {
      const int cl = t >> 2, dq = (t & 3) * 16;
      unsigned short* dst = wkT + (size_t)(h * 1152 + ct * 64 + cl) * 128 + dt * 64 + dq;
      u16x8 o0, o1;
#pragma unroll
      for (int e = 0; e < 8; ++e) {
        o0[e] = f2bf(tl2[(dq + e) * 65 + cl]);
        o1[e] = f2bf(tl2[(dq + 8 + e) * 65 + cl]);
      }
      *reinterpret_cast<u16x8*>(dst) = o0;
      *reinterpret_cast<u16x8*>(dst + 8) = o1;
    }
  } else if (bid < 1288) {
    // wkT rows 1024..1151: row 1024 = k-bias, rest zero
    const int h = bid - 1280;
    for (int idx = t; idx < 16384; idx += 256) {
      const int row = 1024 + (idx >> 7), d = idx & 127;
      unsigned short v = 0;
      if (row == 1024) v = f2bf(qkv_b[1024 + h * 128 + d]);
      wkT[(size_t)(h * 1152 + row) * 128 + d] = v;
    }
  } else {
    const int idx = (bid - 1288) * 256 + t;  // 16384
    const int m = idx >> 8, j = idx & 255;
    const float band = exp2f((float)(m & 31) * KSTEP) * PI_F;
    const float coord = (m < 32) ? (-1.0f + (2.0f / 15.0f) * (float)(j >> 4))
                                 : (-1.0f + (2.0f / 15.0f) * (float)(j & 15));
    float sn, cs;
    sincosf(coord * band, &sn, &cs);
    sc[idx] = make_float2(sn, cs);
  }
}

// ---------------- split-K skinny GEMM: Cp[kc] = A * B^T (K-chunk = 256) ----------------
__global__ __launch_bounds__(256) void gemm_splitk(
    const float* __restrict__ A, int lda, int aStrideZ,
    const float* __restrict__ B, int ldb, int bStrideZ,
    float* __restrict__ Cp, int ldc, int cStrideZ, int cStrideKc, int KC) {
  const int nt = blockIdx.x, mt = blockIdx.y;
  const int z = blockIdx.z / KC, kc = blockIdx.z % KC;
  const int tid = threadIdx.x;
  A += (size_t)z * aStrideZ + (size_t)mt * 32 * lda + kc * 256;
  B += (size_t)z * bStrideZ + (size_t)nt * 64 * ldb + kc * 256;
  Cp += (size_t)kc * cStrideKc + (size_t)z * cStrideZ + (size_t)mt * 32 * ldc + nt * 64;

  __shared__ float As[32][34];
  __shared__ float Bs[32][68];

  const int tm = tid >> 4;
  const int tn = tid & 15;
  float acc0[4] = {0, 0, 0, 0}, acc1[4] = {0, 0, 0, 0};

  for (int k0 = 0; k0 < 256; k0 += 32) {
    {
      const int m = tid >> 3, kq = tid & 7;
      float4 v = *reinterpret_cast<const float4*>(A + (size_t)m * lda + k0 + kq * 4);
      As[kq * 4 + 0][m] = v.x; As[kq * 4 + 1][m] = v.y;
      As[kq * 4 + 2][m] = v.z; As[kq * 4 + 3][m] = v.w;
    }
#pragma unroll
    for (int r = 0; r < 2; ++r) {
      const int idx = r * 256 + tid;
      const int n = idx >> 3, kq = idx & 7;
      float4 v = *reinterpret_cast<const float4*>(B + (size_t)n * ldb + k0 + kq * 4);
      Bs[kq * 4 + 0][n] = v.x; Bs[kq * 4 + 1][n] = v.y;
      Bs[kq * 4 + 2][n] = v.z; Bs[kq * 4 + 3][n] = v.w;
    }
    __syncthreads();
#pragma unroll
    for (int k = 0; k < 32; ++k) {
      const float a0 = As[k][tm * 2], a1 = As[k][tm * 2 + 1];
      const float4 bb = *reinterpret_cast<const float4*>(&Bs[k][tn * 4]);
      acc0[0] += a0 * bb.x; acc0[1] += a0 * bb.y; acc0[2] += a0 * bb.z; acc0[3] += a0 * bb.w;
      acc1[0] += a1 * bb.x; acc1[1] += a1 * bb.y; acc1[2] += a1 * bb.z; acc1[3] += a1 * bb.w;
    }
    __syncthreads();
  }
  *reinterpret_cast<float4*>(Cp + (size_t)(tm * 2) * ldc + tn * 4) =
      make_float4(acc0[0], acc0[1], acc0[2], acc0[3]);
  *reinterpret_cast<float4*>(Cp + (size_t)(tm * 2 + 1) * ldc + tn * 4) =
      make_float4(acc1[0], acc1[1], acc1[2], acc1[3]);
}

// ---------------- proj GEMM with inline 4-partial A reduce + Wv-bias ----------------
__global__ __launch_bounds__(256) void gemm_proj_splitk(
    const float* __restrict__ Apart, const float* __restrict__ abias,
    const float* __restrict__ B, float* __restrict__ Cp) {
  const int nt = blockIdx.x, mt = blockIdx.y, kc = blockIdx.z;
  const int tid = threadIdx.x;
  B += (size_t)nt * 64 * 1024 + kc * 256;
  Cp += (size_t)kc * 65536 + (size_t)mt * 32 * 1024 + nt * 64;

  __shared__ float As[32][34];
  __shared__ float Bs[32][68];

  const int tm = tid >> 4;
  const int tn = tid & 15;
  float acc0[4] = {0, 0, 0, 0}, acc1[4] = {0, 0, 0, 0};

  for (int k0 = 0; k0 < 256; k0 += 32) {
    {
      const int m = tid >> 3, kq = tid & 7;
      const int kg = kc * 256 + k0 + kq * 4;
      const float* Ab = Apart + (size_t)(mt * 32 + m) * 1024 + kg;
      float4 v = *reinterpret_cast<const float4*>(abias + kg);
#pragma unroll
      for (int r = 0; r < 4; ++r) {
        const float4 p = *reinterpret_cast<const float4*>(Ab + (size_t)r * 65536);
        v.x += p.x; v.y += p.y; v.z += p.z; v.w += p.w;
      }
      As[kq * 4 + 0][m] = v.x; As[kq * 4 + 1][m] = v.y;
      As[kq * 4 + 2][m] = v.z; As[kq * 4 + 3][m] = v.w;
    }
#pragma unroll
    for (int r = 0; r < 2; ++r) {
      const int idx = r * 256 + tid;
      const int n = idx >> 3, kq = idx & 7;
      float4 v = *reinterpret_cast<const float4*>(B + (size_t)n * 1024 + k0 + kq * 4);
      Bs[kq * 4 + 0][n] = v.x; Bs[kq * 4 + 1][n] = v.y;
      Bs[kq * 4 + 2][n] = v.z; Bs[kq * 4 + 3][n] = v.w;
    }
    __syncthreads();
#pragma unroll
    for (int k = 0; k < 32; ++k) {
      const float a0 = As[k][tm * 2], a1 = As[k][tm * 2 + 1];
      const float4 bb = *reinterpret_cast<const float4*>(&Bs[k][tn * 4]);
      acc0[0] += a0 * bb.x; acc0[1] += a0 * bb.y; acc0[2] += a0 * bb.z; acc0[3] += a0 * bb.w;
      acc1[0] += a1 * bb.x; acc1[1] += a1 * bb.y; acc1[2] += a1 * bb.z; acc1[3] += a1 * bb.w;
    }
    __syncthreads();
  }
  *reinterpret_cast<float4*>(Cp + (size_t)(tm * 2) * 1024 + tn * 4) =
      make_float4(acc0[0], acc0[1], acc0[2], acc0[3]);
  *reinterpret_cast<float4*>(Cp + (size_t)(tm * 2 + 1) * 1024 + tn * 4) =
      make_float4(acc1[0], acc1[1], acc1[2], acc1[3]);
}

// ---------------- reduce 4 split-K partials + bias ----------------
__global__ __launch_bounds__(256) void reduce4_bias(const float* __restrict__ part,
                                                    const float* __restrict__ bias,
                                                    float* __restrict__ out) {
  const int i = blockIdx.x * 256 + threadIdx.x;  // 65536
  out[i] = part[i] + part[i + 65536] + part[i + 131072] + part[i + 196608] + bias[i & 1023];
}

// ---------------- T GEMM: T[s][h][b*16+v][c] = (rot_v q0)_half_s . WkT[c] ----------------
__global__ __launch_bounds__(256) void tgemm_rot(
    const unsigned short* __restrict__ wkT, const float* __restrict__ q0p,
    const float* __restrict__ qkv_b, const float2* __restrict__ sc,
    unsigned short* __restrict__ T) {
  const int nt = blockIdx.x;  // 9
  const int mt = blockIdx.y;  // 8
  const int z = blockIdx.z;   // 16
  const int h = z >> 1, s = z & 1;
  const int tid = threadIdx.x;
  const int w = tid >> 6, lane = tid & 63;
  const int wr = w >> 1, wc = w & 1;

  __shared__ __align__(16) char smem[34816];
  char* Ab = smem;                                         // [128 m][128 B]
  char* Bb = smem + 16384;                                 // [128 c][128 B]
  float* q0red = reinterpret_cast<float*>(smem + 32768);   // [8 b][64 d]

  // B stage (gload, pre-swizzled source; 8-slot rows)
#pragma unroll
  for (int i = 0; i < 4; ++i) {
    const int g = w * 4 + i;
    const int row = g * 8 + (lane >> 3);
    const int sl = ((lane & 7) ^ ((row >> 1) & 7)) * 8;
    gload_lds16(wkT + ((size_t)h * 1152 + nt * 128 + row) * 128 + s * 64 + sl, Bb + g * 1024);
  }
  // q0 half reduce (+ q-bias) for this (mt, h, s)
  for (int idx = tid; idx < 512; idx += 256) {
    const int bl = idx >> 6, d = idx & 63;
    const int b = mt * 8 + bl;
    const float* qp = q0p + (size_t)b * 2048 + h * 128 + s * 64 + d;
    q0red[idx] = qkv_b[h * 128 + s * 64 + d] + qp[0] + qp[131072] + qp[262144] + qp[393216];
  }
  __syncthreads();  // q0red visible; B resident (vmcnt drained)

  // A compute: rotated q rows (bf16), swizzled ds_write
  {
    const int r = tid >> 1;             // m-row 0..127
    const int ph = (tid & 1) * 16;      // pair start
    const int v = r & 15;
    const int jrep = (s == 0) ? v * 16 : v;
    const float* qr = q0red + (r >> 4) * 64;
    const int swz = (r >> 1) & 7;
#pragma unroll
    for (int g = 0; g < 4; ++g) {
      unsigned pk[4];
#pragma unroll
      for (int e = 0; e < 4; ++e) {
        const int p = ph + g * 4 + e;
        const float qe = qr[2 * p], qo = qr[2 * p + 1];
        const float2 tt = sc[(s * 32 + p) * 256 + jrep];
        const float ae = qe * tt.y + qo * tt.x;
        const float ao = qo * tt.y - qe * tt.x;
        pk[e] = (unsigned)f2bf(ae) | ((unsigned)f2bf(ao) << 16);
      }
      const int slot = ((ph >> 2) + g) ^ swz;
      *reinterpret_cast<uint4*>(Ab + r * 128 + slot * 16) = make_uint4(pk[0], pk[1], pk[2], pk[3]);
    }
  }
  __syncthreads();

  f32x4 acc[4][4] = {};
#pragma unroll
  for (int kk = 0; kk < 2; ++kk) {
    bf16x8 af[4], bf[4];
#pragma unroll
    for (int mi = 0; mi < 4; ++mi) {
      const int row = wr * 64 + mi * 16 + (lane & 15);
      const int slot = (kk * 4 + (lane >> 4)) ^ ((row >> 1) & 7);
      af[mi] = *reinterpret_cast<const bf16x8*>(Ab + row * 128 + (slot << 4));
    }
#pragma unroll
    for (int ni = 0; ni < 4; ++ni) {
      const int row = wc * 64 + ni * 16 + (lane & 15);
      const int slot = (kk * 4 + (lane >> 4)) ^ ((row >> 1) & 7);
      bf[ni] = *reinterpret_cast<const bf16x8*>(Bb + row * 128 + (slot << 4));
    }
#pragma unroll
    for (int mi = 0; mi < 4; ++mi)
#pragma unroll
      for (int ni = 0; ni < 4; ++ni)
        acc[mi][ni] = __builtin_amdgcn_mfma_f32_16x16x32_bf16(af[mi], bf[ni], acc[mi][ni], 0, 0, 0);
  }

  // C write (bf16): C/D map col=lane&15, row=(lane>>4)*4+rr
  unsigned short* Tz = T + (size_t)(s * 8 + h) * 1024 * 1152;
#pragma unroll
  for (int mi = 0; mi < 4; ++mi)
#pragma unroll
    for (int ni = 0; ni < 4; ++ni) {
      const int col = nt * 128 + wc * 64 + ni * 16 + (lane & 15);
#pragma unroll
      for (int rr = 0; rr < 4; ++rr) {
        const int row = mt * 128 + wr * 64 + mi * 16 + (lane >> 4) * 4 + rr;
        Tz[(size_t)row * 1152 + col] = f2bf(acc[mi][ni][rr]);
      }
    }
}

// ---------------- MFMA scores + fused softmax + u (8-wave, depth-3 pipeline) ----------------
// Block (b, ht=head-pair): P = X_b(256j x 1024c) @ T_b^T(64n x 1024c) via MFMA;
// S[j,h] = P[j, h*32+y_j] + P[j, h*32+16+x_j] + biases; softmax(257) -> attn (LDS);
// u[h][c] = attn @ [t_mean; X_b]. 4 LDS bufs, per-wave counted vmcnt, 0-conflict swizzle.
__global__ __launch_bounds__(512, 1) void scores_u(
    const unsigned short* __restrict__ Tg, const unsigned short* __restrict__ xt,
    const float* __restrict__ q0p, const float* __restrict__ qkv_b,
    const float* __restrict__ t_mean, float* __restrict__ u) {
  const int l = blockIdx.x;  // 256; same-b blocks share an XCD (l&7 preserved)
  const int b = ((l >> 5) << 3) | (l & 7);
  const int ht = (l >> 3) & 3;  // head pair: heads ht*2, ht*2+1
  const int tid = threadIdx.x;
  const int w = tid >> 6, lane = tid & 63;

  __shared__ __align__(16) char smem[81920];  // 4 bufs x (A 16KB + B 4KB)

  const unsigned short* xtb = xt + (size_t)b * 262144;

  // Stage one BK=32 tile. A: 256 j-rows; wave w stages rows w*32..+32 (2 gloads).
  // B: 64 T-rows; waves 0-3 stage rows w*16..+16 (1 gload). Per-wave counts: 3 / 2.
#define STAGE(buf, c0)                                                          \
  {                                                                             \
    char* Ab_ = smem + (buf)*20480;                                             \
    char* Bb_ = Ab_ + 16384;                                                    \
    _Pragma("unroll") for (int i = 0; i < 2; ++i) {                             \
      const int row_ = w * 32 + i * 16 + (lane >> 2);                           \
      const int sl_ = ((lane & 3) ^ ((row_ >> 1) & 3)) * 8;                     \
      gload_lds16(xtb + (size_t)row_ * 1024 + (c0) + sl_,                       \
                  Ab_ + (w * 2 + i) * 1024);                                    \
    }                                                                           \
    if (w < 4) {                                                                \
      const int n_ = w * 16 + (lane >> 2);                                      \
      const int h_ = ht * 2 + (n_ >> 5), s_ = (n_ >> 4) & 1, v_ = n_ & 15;      \
      const size_t rowT_ = ((size_t)(s_ * 8 + h_) * 1024 + b * 16 + v_) * 1152; \
      const int sl_ = ((lane & 3) ^ ((n_ >> 1) & 3)) * 8;                       \
      gload_lds16(Tg + rowT_ + (c0) + sl_, Bb_ + w * 1024);                     \
    }                                                                           \
  }

  STAGE(0, 0);
  STAGE(1, 32);
  STAGE(2, 64);
  f32x4 acc[2][4] = {};
  for (int t = 0; t < 32; ++t) {
    {  // stage tile t+3 (clamped tail keeps vmcnt timeline uniform)
      const int src = (t + 3 > 31) ? 31 : (t + 3);
      STAGE((t + 3) & 3, src * 32);
    }
    if (w < 4)  // 3 gloads/stage, 3 stages in flight after this tile
      asm volatile("s_waitcnt vmcnt(9)" ::: "memory");
    else  // 2 gloads/stage
      asm volatile("s_waitcnt vmcnt(6)" ::: "memory");
    __builtin_amdgcn_s_barrier();
    const char* Ab = smem + (t & 3) * 20480;
    const char* Bb = Ab + 16384;
    bf16x8 af[2], bfr[4];
#pragma unroll
    for (int mi = 0; mi < 2; ++mi) {
      const int row = w * 32 + mi * 16 + (lane & 15);
      af[mi] = *reinterpret_cast<const bf16x8*>(
          Ab + row * 64 + ((((lane >> 4) ^ ((row >> 1) & 3))) << 4));
    }
#pragma unroll
    for (int ni = 0; ni < 4; ++ni) {
      const int n = ni * 16 + (lane & 15);
      bfr[ni] = *reinterpret_cast<const bf16x8*>(
          Bb + n * 64 + ((((lane >> 4) ^ ((n >> 1) & 3))) << 4));
    }
    __builtin_amdgcn_s_setprio(1);
#pragma unroll
    for (int mi = 0; mi < 2; ++mi)
#pragma unroll
      for (int ni = 0; ni < 4; ++ni)
        acc[mi][ni] =
            __builtin_amdgcn_mfma_f32_16x16x32_bf16(af[mi], bfr[ni], acc[mi][ni], 0, 0, 0);
    __builtin_amdgcn_s_setprio(0);
    __builtin_amdgcn_s_barrier();
    asm volatile("" ::: "memory");
  }
#undef STAGE

  asm volatile("s_waitcnt vmcnt(0)" ::: "memory");
  __syncthreads();

  // ---- LDS reuse: epilogue arrays ----
  float* Sp = reinterpret_cast<float*>(smem);   // [256 j][2 h][2 s]
  float* bias = Sp + 1024;                      // [2 h][2 s][16 v]
  float* q0l = bias + 64;                       // [256] (2 heads x 128)
  float* k0l = q0l + 256;                       // [256]
  float* ps = k0l + 256;                        // [4]
  float* smax = ps + 4;                         // [8]
  float* ssum = smax + 8;                       // [8]
  float* attnl = ssum + 8;                      // [2][257]
  float* upart = reinterpret_cast<float*>(smem + 16384);  // [8 w][2 h][1024 c]

  // diagonal extraction: each (j, h, s) slot has exactly one writer lane
#pragma unroll
  for (int mi = 0; mi < 2; ++mi)
#pragma unroll
    for (int ni = 0; ni < 4; ++ni)
#pragma unroll
      for (int rr = 0; rr < 4; ++rr) {
        const int j = w * 32 + mi * 16 + ((lane >> 4) << 2) + rr;
        const int col = ni * 16 + (lane & 15);
        const int s = (col >> 4) & 1;
        const int sel = s ? (j & 15) : (j >> 4);
        if ((col & 15) == sel) Sp[(j * 2 + (col >> 5)) * 2 + s] = acc[mi][ni][rr];
      }
  if (tid < 64) {
    const int h_ = tid >> 5, s_ = (tid >> 4) & 1, v_ = tid & 15;
    bias[tid] =
        bf2f(Tg[((size_t)(s_ * 8 + ht * 2 + h_) * 1024 + b * 16 + v_) * 1152 + 1024]);
  }
  if (tid < 256) {
    const float* qp = q0p + (size_t)b * 2048 + ht * 256 + tid;
    q0l[tid] = qkv_b[ht * 256 + tid] + qp[0] + qp[131072] + qp[262144] + qp[393216];
    const float* kp = qp + 1024;
    k0l[tid] = qkv_b[1024 + ht * 256 + tid] + kp[0] + kp[131072] + kp[262144] + kp[393216];
  }
  __syncthreads();
  if (tid < 256) {
    float pr = q0l[tid] * k0l[tid];
    pr = wave_reduce_sum(pr);
    if (lane == 0) ps[w] = pr;  // w 0,1 -> head0; 2,3 -> head1
  }
  __syncthreads();

  // ---- dual-head softmax over 257 tokens (threads 0..255; tid0 also token 0)
  const float scale = 0.08838834764831845f;
  float e0 = 0.0f, e1 = 0.0f, eb0 = 0.0f, eb1 = 0.0f;
  if (tid < 256) {
    const float va0 = scale * (Sp[tid * 4 + 0] + Sp[tid * 4 + 1] + bias[tid >> 4] +
                               bias[16 + (tid & 15)]);
    const float va1 = scale * (Sp[tid * 4 + 2] + Sp[tid * 4 + 3] + bias[32 + (tid >> 4)] +
                               bias[48 + (tid & 15)]);
    float vb0 = -3.0e38f, vb1 = -3.0e38f;
    if (tid == 0) {
      vb0 = scale * (ps[0] + ps[1]);
      vb1 = scale * (ps[2] + ps[3]);
    }
    float m0 = fmaxf(va0, vb0), m1 = fmaxf(va1, vb1);
#pragma unroll
    for (int off = 32; off; off >>= 1) {
      m0 = fmaxf(m0, __shfl_xor(m0, off));
      m1 = fmaxf(m1, __shfl_xor(m1, off));
    }
    if (lane == 0) { smax[w] = m0; smax[4 + w] = m1; }
  }
  __syncthreads();
  if (tid < 256) {
    const float g0 = fmaxf(fmaxf(smax[0], smax[1]), fmaxf(smax[2], smax[3]));
    const float g1 = fmaxf(fmaxf(smax[4], smax[5]), fmaxf(smax[6], smax[7]));
    const float va0 = scale * (Sp[tid * 4 + 0] + Sp[tid * 4 + 1] + bias[tid >> 4] +
                               bias[16 + (tid & 15)]);
    const float va1 = scale * (Sp[tid * 4 + 2] + Sp[tid * 4 + 3] + bias[32 + (tid >> 4)] +
                               bias[48 + (tid & 15)]);
    e0 = expf(va0 - g0);
    e1 = expf(va1 - g1);
    if (tid == 0) {
      eb0 = expf(scale * (ps[0] + ps[1]) - g0);
      eb1 = expf(scale * (ps[2] + ps[3]) - g1);
    }
    float s0 = e0 + eb0, s1 = e1 + eb1;
#pragma unroll
    for (int off = 32; off; off >>= 1) {
      s0 += __shfl_xor(s0, off);
      s1 += __shfl_xor(s1, off);
    }
    if (lane == 0) { ssum[w] = s0; ssum[4 + w] = s1; }
  }
  __syncthreads();
  if (tid < 256) {
    const float inv0 = 1.0f / (ssum[0] + ssum[1] + ssum[2] + ssum[3]);
    const float inv1 = 1.0f / (ssum[4] + ssum[5] + ssum[6] + ssum[7]);
    attnl[1 + tid] = e0 * inv0;
    attnl[257 + 1 + tid] = e1 * inv1;
    if (tid == 0) { attnl[0] = eb0 * inv0; attnl[257] = eb1 * inv1; }
  }
  __syncthreads();

  // ---- u: wave w accumulates its 32 j over all 1024 c (lane owns 16 c)
  {
    float ua0[16] = {}, ua1[16] = {};
    const unsigned short* xr = xtb + (size_t)(w * 32) * 1024 + lane * 16;
    for (int jj = 0; jj < 32; ++jj) {
      const float a0 = attnl[1 + w * 32 + jj];
      const float a1 = attnl[257 + 1 + w * 32 + jj];
      const u16x8 v0 = *reinterpret_cast<const u16x8*>(xr + (size_t)jj * 1024);
      const u16x8 v1 = *reinterpret_cast<const u16x8*>(xr + (size_t)jj * 1024 + 8);
#pragma unroll
      for (int e = 0; e < 8; ++e) {
        const float f0 = bf2f((unsigned short)v0[e]);
        const float f1 = bf2f((unsigned short)v1[e]);
        ua0[e] += a0 * f0; ua0[8 + e] += a0 * f1;
        ua1[e] += a1 * f0; ua1[8 + e] += a1 * f1;
      }
    }
#pragma unroll
    for (int e = 0; e < 16; ++e) {
      upart[(w * 2 + 0) * 1024 + lane * 16 + e] = ua0[e];
      upart[(w * 2 + 1) * 1024 + lane * 16 + e] = ua1[e];
    }
  }
  __syncthreads();
#pragma unroll
  for (int r = 0; r < 4; ++r) {
    const int o = tid * 4 + r;  // 0..2047
    const int h2 = o >> 10, c = o & 1023;
    float s = 0.0f;
#pragma unroll
    for (int ww = 0; ww < 8; ++ww) s += upart[(ww * 2 + h2) * 1024 + c];
    s += attnl[h2 * 257] * t_mean[b * 1024 + c];
    u[((size_t)b * 8 + ht * 2 + h2) * 1024 + c] = s;
  }
}

// ---------------- host side ----------------
extern "C" void kernel_launch(void* const* d_in, const int* in_sizes, int n_in,
                              void* d_out, int out_size, void* d_ws, size_t ws_size,
                              hipStream_t stream) {
  const float* x = (const float*)d_in[0];
  const float* qkv_w = (const float*)d_in[1];
  const float* qkv_b = (const float*)d_in[2];
  const float* proj_w = (const float*)d_in[3];
  const float* proj_b = (const float*)d_in[4];
  float* out = (float*)d_out;

  float* ws = (float*)d_ws;
  float* t_mean = ws;                                       // [0, 65536)
  float* q0k0_part = ws + 65536;                            // [65536, 589824)
  float* u = ws + 589824;                                   // [589824, 1114112)
  float* out0_part = ws + 1114112;                          // [1114112, 1376256)
  float* out_part = ws + 1376256;                           // [1376256, 1638400)
  float2* sc = (float2*)(ws + 1638400);                     // [1638400, 1671168)
  unsigned short* wkT = (unsigned short*)(ws + 1671168);    // 1179648 u16 = [1671168, 2260992)
  unsigned short* T = (unsigned short*)(ws + 2260992);      // 18874368 u16 = [2260992, 11698176)
  unsigned short* x_t = (unsigned short*)(ws + 11698176);   // 16777216 u16 = [11698176, 20086784)

  // 1. fused prep: x->x_t+mean | wkT transpose | wkT bias rows | sc table
  prep_kernel<<<1352, 256, 0, stream>>>(x, qkv_w, qkv_b, x_t, t_mean, wkT, sc);

  // 2. q0k0 partials: t_mean @ qkv_w[0:2048].T  (M=64,N=2048,K=4x256)
  gemm_splitk<<<dim3(32, 2, 4), 256, 0, stream>>>(t_mean, 1024, 0, qkv_w, 1024, 0,
                                                  q0k0_part, 2048, 0, 131072, 4);

  // 3. T = rotated-q0 @ WkT (factorized RoPE; M=1024,N=1152,K=64, per h,half)
  tgemm_rot<<<dim3(9, 8, 16), 256, 0, stream>>>(wkT, q0k0_part, qkv_b, sc, T);

  // 4. MFMA scores + softmax + u  (256 blocks = (b, head-pair), 8 waves)
  scores_u<<<256, 512, 0, stream>>>(T, x_t, q0k0_part, qkv_b, t_mean, u);

  // 5. out0 partials: per-head Wv_h . u  (Z=8, K=4x256)
  gemm_splitk<<<dim3(2, 2, 32), 256, 0, stream>>>(u, 8192, 1024,
                                                  qkv_w + (size_t)2048 * 1024, 1024, 131072,
                                                  out0_part, 1024, 128, 65536, 4);

  // 6. proj partials, A = reduce4(out0_part)+bias_v inline
  gemm_proj_splitk<<<dim3(16, 2, 4), 256, 0, stream>>>(out0_part, qkv_b + 2048, proj_w, out_part);

  // 7. final reduce + proj bias
  reduce4_bias<<<256, 256, 0, stream>>>(out_part, proj_b, out);
}

// Round 11
// 100.174 us; speedup vs baseline: 1.5989x; 1.0170x over previous
//
#include <hip/hip_runtime.h>
#include <math.h>

#define PI_F 3.14159265358979323846f
#define KSTEP 0.21959209425992272f /* (log2(224)-1)/31 */

using bf16x8 = __attribute__((ext_vector_type(8))) short;
using f32x4 = __attribute__((ext_vector_type(4))) float;
using u16x8 = __attribute__((ext_vector_type(8))) unsigned short;

static __device__ __forceinline__ float wave_reduce_sum(float v) {
#pragma unroll
  for (int off = 32; off; off >>= 1) v += __shfl_down(v, off);
  return v;
}

static __device__ __forceinline__ unsigned short f2bf(float f) {
  unsigned u = __float_as_uint(f);
  return (unsigned short)((u + 0x7fffu + ((u >> 16) & 1u)) >> 16);
}

static __device__ __forceinline__ float bf2f(unsigned short s) {
  return __uint_as_float(((unsigned)s) << 16);
}

static __device__ __forceinline__ void gload_lds16(const void* g, void* l) {
  __builtin_amdgcn_global_load_lds((const __attribute__((address_space(1))) unsigned int*)g,
                                   (__attribute__((address_space(3))) unsigned int*)l, 16, 0, 0);
}

// ---- fused prep: x->bf16 x_t + t_mean | wkT (transposed Wk + bias row) | sc table ----
__global__ __launch_bounds__(256) void prep_kernel(const float* __restrict__ x,
                                                   const float* __restrict__ qkv_w,
                                                   const float* __restrict__ qkv_b,
                                                   unsigned short* __restrict__ xt,
                                                   float* __restrict__ t_mean,
                                                   unsigned short* __restrict__ wkT,
                                                   float2* __restrict__ sc) {
  const int bid = blockIdx.x;
  const int t = threadIdx.x;
  __shared__ float tile[64 * 33];
  __shared__ float tl2[64 * 65];
  if (bid < 1024) {
    const int ct = bid & 15, b = bid >> 4;
    const int cl = t >> 2, pq = (t & 3) * 8;  // read role
    const int pl = t >> 3, cq = (t & 7) * 8;  // write role
    float sum = 0.0f;
    const float* xrow = x + ((size_t)(b * 1024 + ct * 64 + cl) * 256) + pq;
    unsigned short* xtb = xt + (size_t)b * 262144 + ct * 64;
    for (int pt = 0; pt < 8; ++pt) {
      const float4 v0 = *reinterpret_cast<const float4*>(xrow + pt * 32);
      const float4 v1 = *reinterpret_cast<const float4*>(xrow + pt * 32 + 4);
      tile[cl * 33 + pq + 0] = v0.x; tile[cl * 33 + pq + 1] = v0.y;
      tile[cl * 33 + pq + 2] = v0.z; tile[cl * 33 + pq + 3] = v0.w;
      tile[cl * 33 + pq + 4] = v1.x; tile[cl * 33 + pq + 5] = v1.y;
      tile[cl * 33 + pq + 6] = v1.z; tile[cl * 33 + pq + 7] = v1.w;
      sum += (v0.x + v0.y) + (v0.z + v0.w) + (v1.x + v1.y) + (v1.z + v1.w);
      __syncthreads();
      u16x8 o;
#pragma unroll
      for (int e = 0; e < 8; ++e) o[e] = f2bf(tile[(cq + e) * 33 + pl]);
      *reinterpret_cast<u16x8*>(xtb + (size_t)(pt * 32 + pl) * 1024 + cq) = o;
      __syncthreads();
    }
    sum += __shfl_xor(sum, 1);
    sum += __shfl_xor(sum, 2);
    if ((t & 3) == 0) t_mean[b * 1024 + ct * 64 + cl] = sum * (1.0f / 256.0f);
  } else if (bid < 1280) {
    // wkT[h][c][d] transpose tiles: bf16, c rows, d contiguous
    const int bb = bid - 1024;
    const int h = bb >> 5, t5 = bb & 31;
    const int dt = t5 >> 4, ct = t5 & 15;
    {
      const int dl = t >> 2, cq = (t & 3) * 16;
      const float* src = qkv_w + (size_t)(1024 + h * 128 + dt * 64 + dl) * 1024 + ct * 64 + cq;
#pragma unroll
      for (int i = 0; i < 4; ++i) {
        const float4 v = *reinterpret_cast<const float4*>(src + i * 4);
        tl2[dl * 65 + cq + i * 4 + 0] = v.x; tl2[dl * 65 + cq + i * 4 + 1] = v.y;
        tl2[dl * 65 + cq + i * 4 + 2] = v.z; tl2[dl * 65 + cq + i * 4 + 3] = v.w;
      }
    }
    __syncthreads();
    {
      const int cl = t >> 2, dq = (t & 3) * 16;
      unsigned short* dst = wkT + (size_t)(h * 1152 + ct * 64 + cl) * 128 + dt * 64 + dq;
      u16x8 o0, o1;
#pragma unroll
      for (int e = 0; e < 8; ++e) {
        o0[e] = f2bf(tl2[(dq + e) * 65 + cl]);
        o1[e] = f2bf(tl2[(dq + 8 + e) * 65 + cl]);
      }
      *reinterpret_cast<u16x8*>(dst) = o0;
      *reinterpret_cast<u16x8*>(dst + 8) = o1;
    }
  } else if (bid < 1288) {
    // wkT rows 1024..1151: row 1024 = k-bias, rest zero
    const int h = bid - 1280;
    for (int idx = t; idx < 16384; idx += 256) {
      const int row = 1024 + (idx >> 7), d = idx & 127;
      unsigned short v = 0;
      if (row == 1024) v = f2bf(qkv_b[1024 + h * 128 + d]);
      wkT[(size_t)(h * 1152 + row) * 128 + d] = v;
    }
  } else {
    const int idx = (bid - 1288) * 256 + t;  // 16384
    const int m = idx >> 8, j = idx & 255;
    const float band = exp2f((float)(m & 31) * KSTEP) * PI_F;
    const float coord = (m < 32) ? (-1.0f + (2.0f / 15.0f) * (float)(j >> 4))
                                 : (-1.0f + (2.0f / 15.0f) * (float)(j & 15));
    float sn, cs;
    sincosf(coord * band, &sn, &cs);
    sc[idx] = make_float2(sn, cs);
  }
}

// ---------------- split-K skinny GEMM: Cp[kc] = A * B^T (K-chunk = 256) ----------------
__global__ __launch_bounds__(256) void gemm_splitk(
    const float* __restrict__ A, int lda, int aStrideZ,
    const float* __restrict__ B, int ldb, int bStrideZ,
    float* __restrict__ Cp, int ldc, int cStrideZ, int cStrideKc, int KC) {
  const int nt = blockIdx.x, mt = blockIdx.y;
  const int z = blockIdx.z / KC, kc = blockIdx.z % KC;
  const int tid = threadIdx.x;
  A += (size_t)z * aStrideZ + (size_t)mt * 32 * lda + kc * 256;
  B += (size_t)z * bStrideZ + (size_t)nt * 64 * ldb + kc * 256;
  Cp += (size_t)kc * cStrideKc + (size_t)z * cStrideZ + (size_t)mt * 32 * ldc + nt * 64;

  __shared__ float As[32][34];
  __shared__ float Bs[32][68];

  const int tm = tid >> 4;
  const int tn = tid & 15;
  float acc0[4] = {0, 0, 0, 0}, acc1[4] = {0, 0, 0, 0};

  for (int k0 = 0; k0 < 256; k0 += 32) {
    {
      const int m = tid >> 3, kq = tid & 7;
      float4 v = *reinterpret_cast<const float4*>(A + (size_t)m * lda + k0 + kq * 4);
      As[kq * 4 + 0][m] = v.x; As[kq * 4 + 1][m] = v.y;
      As[kq * 4 + 2][m] = v.z; As[kq * 4 + 3][m] = v.w;
    }
#pragma unroll
    for (int r = 0; r < 2; ++r) {
      const int idx = r * 256 + tid;
      const int n = idx >> 3, kq = idx & 7;
      float4 v = *reinterpret_cast<const float4*>(B + (size_t)n * ldb + k0 + kq * 4);
      Bs[kq * 4 + 0][n] = v.x; Bs[kq * 4 + 1][n] = v.y;
      Bs[kq * 4 + 2][n] = v.z; Bs[kq * 4 + 3][n] = v.w;
    }
    __syncthreads();
#pragma unroll
    for (int k = 0; k < 32; ++k) {
      const float a0 = As[k][tm * 2], a1 = As[k][tm * 2 + 1];
      const float4 bb = *reinterpret_cast<const float4*>(&Bs[k][tn * 4]);
      acc0[0] += a0 * bb.x; acc0[1] += a0 * bb.y; acc0[2] += a0 * bb.z; acc0[3] += a0 * bb.w;
      acc1[0] += a1 * bb.x; acc1[1] += a1 * bb.y; acc1[2] += a1 * bb.z; acc1[3] += a1 * bb.w;
    }
    __syncthreads();
  }
  *reinterpret_cast<float4*>(Cp + (size_t)(tm * 2) * ldc + tn * 4) =
      make_float4(acc0[0], acc0[1], acc0[2], acc0[3]);
  *reinterpret_cast<float4*>(Cp + (size_t)(tm * 2 + 1) * ldc + tn * 4) =
      make_float4(acc1[0], acc1[1], acc1[2], acc1[3]);
}

// ---------------- proj GEMM with inline 4-partial A reduce + Wv-bias ----------------
__global__ __launch_bounds__(256) void gemm_proj_splitk(
    const float* __restrict__ Apart, const float* __restrict__ abias,
    const float* __restrict__ B, float* __restrict__ Cp) {
  const int nt = blockIdx.x, mt = blockIdx.y, kc = blockIdx.z;
  const int tid = threadIdx.x;
  B += (size_t)nt * 64 * 1024 + kc * 256;
  Cp += (size_t)kc * 65536 + (size_t)mt * 32 * 1024 + nt * 64;

  __shared__ float As[32][34];
  __shared__ float Bs[32][68];

  const int tm = tid >> 4;
  const int tn = tid & 15;
  float acc0[4] = {0, 0, 0, 0}, acc1[4] = {0, 0, 0, 0};

  for (int k0 = 0; k0 < 256; k0 += 32) {
    {
      const int m = tid >> 3, kq = tid & 7;
      const int kg = kc * 256 + k0 + kq * 4;
      const float* Ab = Apart + (size_t)(mt * 32 + m) * 1024 + kg;
      float4 v = *reinterpret_cast<const float4*>(abias + kg);
#pragma unroll
      for (int r = 0; r < 4; ++r) {
        const float4 p = *reinterpret_cast<const float4*>(Ab + (size_t)r * 65536);
        v.x += p.x; v.y += p.y; v.z += p.z; v.w += p.w;
      }
      As[kq * 4 + 0][m] = v.x; As[kq * 4 + 1][m] = v.y;
      As[kq * 4 + 2][m] = v.z; As[kq * 4 + 3][m] = v.w;
    }
#pragma unroll
    for (int r = 0; r < 2; ++r) {
      const int idx = r * 256 + tid;
      const int n = idx >> 3, kq = idx & 7;
      float4 v = *reinterpret_cast<const float4*>(B + (size_t)n * 1024 + k0 + kq * 4);
      Bs[kq * 4 + 0][n] = v.x; Bs[kq * 4 + 1][n] = v.y;
      Bs[kq * 4 + 2][n] = v.z; Bs[kq * 4 + 3][n] = v.w;
    }
    __syncthreads();
#pragma unroll
    for (int k = 0; k < 32; ++k) {
      const float a0 = As[k][tm * 2], a1 = As[k][tm * 2 + 1];
      const float4 bb = *reinterpret_cast<const float4*>(&Bs[k][tn * 4]);
      acc0[0] += a0 * bb.x; acc0[1] += a0 * bb.y; acc0[2] += a0 * bb.z; acc0[3] += a0 * bb.w;
      acc1[0] += a1 * bb.x; acc1[1] += a1 * bb.y; acc1[2] += a1 * bb.z; acc1[3] += a1 * bb.w;
    }
    __syncthreads();
  }
  *reinterpret_cast<float4*>(Cp + (size_t)(tm * 2) * 1024 + tn * 4) =
      make_float4(acc0[0], acc0[1], acc0[2], acc0[3]);
  *reinterpret_cast<float4*>(Cp + (size_t)(tm * 2 + 1) * 1024 + tn * 4) =
      make_float4(acc1[0], acc1[1], acc1[2], acc1[3]);
}

// ---------------- reduce 4 split-K partials + bias ----------------
__global__ __launch_bounds__(256) void reduce4_bias(const float* __restrict__ part,
                                                    const float* __restrict__ bias,
                                                    float* __restrict__ out) {
  const int i = blockIdx.x * 256 + threadIdx.x;  // 65536
  out[i] = part[i] + part[i + 65536] + part[i + 131072] + part[i + 196608] + bias[i & 1023];
}

// ---------------- T GEMM: T[s][h][b*16+v][c] = (rot_v q0)_half_s . WkT[c] ----------------
__global__ __launch_bounds__(256) void tgemm_rot(
    const unsigned short* __restrict__ wkT, const float* __restrict__ q0p,
    const float* __restrict__ qkv_b, const float2* __restrict__ sc,
    unsigned short* __restrict__ T) {
  const int nt = blockIdx.x;  // 9
  const int mt = blockIdx.y;  // 8
  const int z = blockIdx.z;   // 16
  const int h = z >> 1, s = z & 1;
  const int tid = threadIdx.x;
  const int w = tid >> 6, lane = tid & 63;
  const int wr = w >> 1, wc = w & 1;

  __shared__ __align__(16) char smem[34816];
  char* Ab = smem;                                         // [128 m][128 B]
  char* Bb = smem + 16384;                                 // [128 c][128 B]
  float* q0red = reinterpret_cast<float*>(smem + 32768);   // [8 b][64 d]

  // B stage (gload, pre-swizzled source; 8-slot rows)
#pragma unroll
  for (int i = 0; i < 4; ++i) {
    const int g = w * 4 + i;
    const int row = g * 8 + (lane >> 3);
    const int sl = ((lane & 7) ^ ((row >> 1) & 7)) * 8;
    gload_lds16(wkT + ((size_t)h * 1152 + nt * 128 + row) * 128 + s * 64 + sl, Bb + g * 1024);
  }
  // q0 half reduce (+ q-bias) for this (mt, h, s)
  for (int idx = tid; idx < 512; idx += 256) {
    const int bl = idx >> 6, d = idx & 63;
    const int b = mt * 8 + bl;
    const float* qp = q0p + (size_t)b * 2048 + h * 128 + s * 64 + d;
    q0red[idx] = qkv_b[h * 128 + s * 64 + d] + qp[0] + qp[131072] + qp[262144] + qp[393216];
  }
  __syncthreads();  // q0red visible; B resident (vmcnt drained)

  // A compute: rotated q rows (bf16), swizzled ds_write
  {
    const int r = tid >> 1;             // m-row 0..127
    const int ph = (tid & 1) * 16;      // pair start
    const int v = r & 15;
    const int jrep = (s == 0) ? v * 16 : v;
    const float* qr = q0red + (r >> 4) * 64;
    const int swz = (r >> 1) & 7;
#pragma unroll
    for (int g = 0; g < 4; ++g) {
      unsigned pk[4];
#pragma unroll
      for (int e = 0; e < 4; ++e) {
        const int p = ph + g * 4 + e;
        const float qe = qr[2 * p], qo = qr[2 * p + 1];
        const float2 tt = sc[(s * 32 + p) * 256 + jrep];
        const float ae = qe * tt.y + qo * tt.x;
        const float ao = qo * tt.y - qe * tt.x;
        pk[e] = (unsigned)f2bf(ae) | ((unsigned)f2bf(ao) << 16);
      }
      const int slot = ((ph >> 2) + g) ^ swz;
      *reinterpret_cast<uint4*>(Ab + r * 128 + slot * 16) = make_uint4(pk[0], pk[1], pk[2], pk[3]);
    }
  }
  __syncthreads();

  f32x4 acc[4][4] = {};
#pragma unroll
  for (int kk = 0; kk < 2; ++kk) {
    bf16x8 af[4], bf[4];
#pragma unroll
    for (int mi = 0; mi < 4; ++mi) {
      const int row = wr * 64 + mi * 16 + (lane & 15);
      const int slot = (kk * 4 + (lane >> 4)) ^ ((row >> 1) & 7);
      af[mi] = *reinterpret_cast<const bf16x8*>(Ab + row * 128 + (slot << 4));
    }
#pragma unroll
    for (int ni = 0; ni < 4; ++ni) {
      const int row = wc * 64 + ni * 16 + (lane & 15);
      const int slot = (kk * 4 + (lane >> 4)) ^ ((row >> 1) & 7);
      bf[ni] = *reinterpret_cast<const bf16x8*>(Bb + row * 128 + (slot << 4));
    }
#pragma unroll
    for (int mi = 0; mi < 4; ++mi)
#pragma unroll
      for (int ni = 0; ni < 4; ++ni)
        acc[mi][ni] = __builtin_amdgcn_mfma_f32_16x16x32_bf16(af[mi], bf[ni], acc[mi][ni], 0, 0, 0);
  }

  // C write (bf16): C/D map col=lane&15, row=(lane>>4)*4+rr
  unsigned short* Tz = T + (size_t)(s * 8 + h) * 1024 * 1152;
#pragma unroll
  for (int mi = 0; mi < 4; ++mi)
#pragma unroll
    for (int ni = 0; ni < 4; ++ni) {
      const int col = nt * 128 + wc * 64 + ni * 16 + (lane & 15);
#pragma unroll
      for (int rr = 0; rr < 4; ++rr) {
        const int row = mt * 128 + wr * 64 + mi * 16 + (lane >> 4) * 4 + rr;
        Tz[(size_t)row * 1152 + col] = f2bf(acc[mi][ni][rr]);
      }
    }
}

// ---------------- MFMA scores + fused softmax + u (8-wave, BK=64, depth-2) ----------------
// Block (b, ht=head-pair): P = X_b(256j x 1024c) @ T_b^T(64n x 1024c) via MFMA;
// S[j,h] = P[j, h*32+y_j] + P[j, h*32+16+x_j] + biases; softmax(257) -> attn (LDS);
// u[h][c] = attn @ [t_mean; X_b]. 3 LDS bufs x 40KB, uniform 5 gloads/wave/stage,
// counted vmcnt(10), 8-slot XOR swizzle (tgemm_rot pattern).
__global__ __launch_bounds__(512, 1) void scores_u(
    const unsigned short* __restrict__ Tg, const unsigned short* __restrict__ xt,
    const float* __restrict__ q0p, const float* __restrict__ qkv_b,
    const float* __restrict__ t_mean, float* __restrict__ u) {
  const int l = blockIdx.x;  // 256; same-b blocks share an XCD (l&7 preserved)
  const int b = ((l >> 5) << 3) | (l & 7);
  const int ht = (l >> 3) & 3;  // head pair: heads ht*2, ht*2+1
  const int tid = threadIdx.x;
  const int w = tid >> 6, lane = tid & 63;

  __shared__ __align__(16) char smem[122880];  // 3 bufs x (A 32KB + B 8KB)

  const unsigned short* xtb = xt + (size_t)b * 262144;

  // Stage one BK=64 tile. A: 256 j-rows (128 B each); wave w stages rows w*32..+32
  // (4 gloads, 8 rows each). B: 64 T-rows; wave w stages rows w*8..+8 (1 gload).
#define STAGE(buf, c0)                                                          \
  {                                                                             \
    char* Ab_ = smem + (buf)*40960;                                             \
    char* Bb_ = Ab_ + 32768;                                                    \
    _Pragma("unroll") for (int i = 0; i < 4; ++i) {                             \
      const int row_ = w * 32 + i * 8 + (lane >> 3);                            \
      const int sl_ = ((lane & 7) ^ ((row_ >> 1) & 7)) * 8;                     \
      gload_lds16(xtb + (size_t)row_ * 1024 + (c0) + sl_,                       \
                  Ab_ + (w * 4 + i) * 1024);                                    \
    }                                                                           \
    {                                                                           \
      const int n_ = w * 8 + (lane >> 3);                                       \
      const int h_ = ht * 2 + (n_ >> 5), s_ = (n_ >> 4) & 1, v_ = n_ & 15;      \
      const size_t rowT_ = ((size_t)(s_ * 8 + h_) * 1024 + b * 16 + v_) * 1152; \
      const int sl_ = ((lane & 7) ^ ((n_ >> 1) & 7)) * 8;                       \
      gload_lds16(Tg + rowT_ + (c0) + sl_, Bb_ + w * 1024);                     \
    }                                                                           \
  }

  STAGE(0, 0);
  STAGE(1, 64);
  f32x4 acc[2][4] = {};
  for (int t = 0; t < 16; ++t) {
    {  // stage tile t+2 (clamped tail keeps vmcnt timeline uniform)
      const int src = (t + 2 > 15) ? 15 : (t + 2);
      STAGE((t + 2) % 3, src * 64);
    }
    asm volatile("s_waitcnt vmcnt(10)" ::: "memory");  // tile t resident; 2 in flight
    __builtin_amdgcn_s_barrier();
    const char* Ab = smem + (t % 3) * 40960;
    const char* Bb = Ab + 32768;
#pragma unroll
    for (int kk = 0; kk < 2; ++kk) {
      bf16x8 af[2], bfr[4];
#pragma unroll
      for (int mi = 0; mi < 2; ++mi) {
        const int row = w * 32 + mi * 16 + (lane & 15);
        const int slot = (kk * 4 + (lane >> 4)) ^ ((row >> 1) & 7);
        af[mi] = *reinterpret_cast<const bf16x8*>(Ab + row * 128 + (slot << 4));
      }
#pragma unroll
      for (int ni = 0; ni < 4; ++ni) {
        const int n = ni * 16 + (lane & 15);
        const int slot = (kk * 4 + (lane >> 4)) ^ ((n >> 1) & 7);
        bfr[ni] = *reinterpret_cast<const bf16x8*>(Bb + n * 128 + (slot << 4));
      }
      __builtin_amdgcn_s_setprio(1);
#pragma unroll
      for (int mi = 0; mi < 2; ++mi)
#pragma unroll
        for (int ni = 0; ni < 4; ++ni)
          acc[mi][ni] =
              __builtin_amdgcn_mfma_f32_16x16x32_bf16(af[mi], bfr[ni], acc[mi][ni], 0, 0, 0);
      __builtin_amdgcn_s_setprio(0);
    }
    __builtin_amdgcn_s_barrier();
    asm volatile("" ::: "memory");
  }
#undef STAGE

  asm volatile("s_waitcnt vmcnt(0)" ::: "memory");
  __syncthreads();

  // ---- LDS reuse: epilogue arrays ----
  float* Sp = reinterpret_cast<float*>(smem);   // [256 j][2 h][2 s]
  float* bias = Sp + 1024;                      // [2 h][2 s][16 v]
  float* q0l = bias + 64;                       // [256] (2 heads x 128)
  float* k0l = q0l + 256;                       // [256]
  float* ps = k0l + 256;                        // [4]
  float* smax = ps + 4;                         // [8]
  float* ssum = smax + 8;                       // [8]
  float* attnl = ssum + 8;                      // [2][257]
  float* upart = reinterpret_cast<float*>(smem + 16384);  // [8 w][2 h][1024 c]

  // diagonal extraction: each (j, h, s) slot has exactly one writer lane
#pragma unroll
  for (int mi = 0; mi < 2; ++mi)
#pragma unroll
    for (int ni = 0; ni < 4; ++ni)
#pragma unroll
      for (int rr = 0; rr < 4; ++rr) {
        const int j = w * 32 + mi * 16 + ((lane >> 4) << 2) + rr;
        const int col = ni * 16 + (lane & 15);
        const int s = (col >> 4) & 1;
        const int sel = s ? (j & 15) : (j >> 4);
        if ((col & 15) == sel) Sp[(j * 2 + (col >> 5)) * 2 + s] = acc[mi][ni][rr];
      }
  if (tid < 64) {
    const int h_ = tid >> 5, s_ = (tid >> 4) & 1, v_ = tid & 15;
    bias[tid] =
        bf2f(Tg[((size_t)(s_ * 8 + ht * 2 + h_) * 1024 + b * 16 + v_) * 1152 + 1024]);
  }
  if (tid < 256) {
    const float* qp = q0p + (size_t)b * 2048 + ht * 256 + tid;
    q0l[tid] = qkv_b[ht * 256 + tid] + qp[0] + qp[131072] + qp[262144] + qp[393216];
    const float* kp = qp + 1024;
    k0l[tid] = qkv_b[1024 + ht * 256 + tid] + kp[0] + kp[131072] + kp[262144] + kp[393216];
  }
  __syncthreads();
  if (tid < 256) {
    float pr = q0l[tid] * k0l[tid];
    pr = wave_reduce_sum(pr);
    if (lane == 0) ps[w] = pr;  // w 0,1 -> head0; 2,3 -> head1
  }
  __syncthreads();

  // ---- dual-head softmax over 257 tokens (threads 0..255; tid0 also token 0)
  const float scale = 0.08838834764831845f;
  float e0 = 0.0f, e1 = 0.0f, eb0 = 0.0f, eb1 = 0.0f;
  if (tid < 256) {
    const float va0 = scale * (Sp[tid * 4 + 0] + Sp[tid * 4 + 1] + bias[tid >> 4] +
                               bias[16 + (tid & 15)]);
    const float va1 = scale * (Sp[tid * 4 + 2] + Sp[tid * 4 + 3] + bias[32 + (tid >> 4)] +
                               bias[48 + (tid & 15)]);
    float vb0 = -3.0e38f, vb1 = -3.0e38f;
    if (tid == 0) {
      vb0 = scale * (ps[0] + ps[1]);
      vb1 = scale * (ps[2] + ps[3]);
    }
    float m0 = fmaxf(va0, vb0), m1 = fmaxf(va1, vb1);
#pragma unroll
    for (int off = 32; off; off >>= 1) {
      m0 = fmaxf(m0, __shfl_xor(m0, off));
      m1 = fmaxf(m1, __shfl_xor(m1, off));
    }
    if (lane == 0) { smax[w] = m0; smax[4 + w] = m1; }
  }
  __syncthreads();
  if (tid < 256) {
    const float g0 = fmaxf(fmaxf(smax[0], smax[1]), fmaxf(smax[2], smax[3]));
    const float g1 = fmaxf(fmaxf(smax[4], smax[5]), fmaxf(smax[6], smax[7]));
    const float va0 = scale * (Sp[tid * 4 + 0] + Sp[tid * 4 + 1] + bias[tid >> 4] +
                               bias[16 + (tid & 15)]);
    const float va1 = scale * (Sp[tid * 4 + 2] + Sp[tid * 4 + 3] + bias[32 + (tid >> 4)] +
                               bias[48 + (tid & 15)]);
    e0 = expf(va0 - g0);
    e1 = expf(va1 - g1);
    if (tid == 0) {
      eb0 = expf(scale * (ps[0] + ps[1]) - g0);
      eb1 = expf(scale * (ps[2] + ps[3]) - g1);
    }
    float s0 = e0 + eb0, s1 = e1 + eb1;
#pragma unroll
    for (int off = 32; off; off >>= 1) {
      s0 += __shfl_xor(s0, off);
      s1 += __shfl_xor(s1, off);
    }
    if (lane == 0) { ssum[w] = s0; ssum[4 + w] = s1; }
  }
  __syncthreads();
  if (tid < 256) {
    const float inv0 = 1.0f / (ssum[0] + ssum[1] + ssum[2] + ssum[3]);
    const float inv1 = 1.0f / (ssum[4] + ssum[5] + ssum[6] + ssum[7]);
    attnl[1 + tid] = e0 * inv0;
    attnl[257 + 1 + tid] = e1 * inv1;
    if (tid == 0) { attnl[0] = eb0 * inv0; attnl[257] = eb1 * inv1; }
  }
  __syncthreads();

  // ---- u: wave w accumulates its 32 j over all 1024 c (lane owns 16 c)
  {
    float ua0[16] = {}, ua1[16] = {};
    const unsigned short* xr = xtb + (size_t)(w * 32) * 1024 + lane * 16;
    for (int jj = 0; jj < 32; ++jj) {
      const float a0 = attnl[1 + w * 32 + jj];
      const float a1 = attnl[257 + 1 + w * 32 + jj];
      const u16x8 v0 = *reinterpret_cast<const u16x8*>(xr + (size_t)jj * 1024);
      const u16x8 v1 = *reinterpret_cast<const u16x8*>(xr + (size_t)jj * 1024 + 8);
#pragma unroll
      for (int e = 0; e < 8; ++e) {
        const float f0 = bf2f((unsigned short)v0[e]);
        const float f1 = bf2f((unsigned short)v1[e]);
        ua0[e] += a0 * f0; ua0[8 + e] += a0 * f1;
        ua1[e] += a1 * f0; ua1[8 + e] += a1 * f1;
      }
    }
#pragma unroll
    for (int e = 0; e < 16; ++e) {
      upart[(w * 2 + 0) * 1024 + lane * 16 + e] = ua0[e];
      upart[(w * 2 + 1) * 1024 + lane * 16 + e] = ua1[e];
    }
  }
  __syncthreads();
#pragma unroll
  for (int r = 0; r < 4; ++r) {
    const int o = tid * 4 + r;  // 0..2047
    const int h2 = o >> 10, c = o & 1023;
    float s = 0.0f;
#pragma unroll
    for (int ww = 0; ww < 8; ++ww) s += upart[(ww * 2 + h2) * 1024 + c];
    s += attnl[h2 * 257] * t_mean[b * 1024 + c];
    u[((size_t)b * 8 + ht * 2 + h2) * 1024 + c] = s;
  }
}

// ---------------- host side ----------------
extern "C" void kernel_launch(void* const* d_in, const int* in_sizes, int n_in,
                              void* d_out, int out_size, void* d_ws, size_t ws_size,
                              hipStream_t stream) {
  const float* x = (const float*)d_in[0];
  const float* qkv_w = (const float*)d_in[1];
  const float* qkv_b = (const float*)d_in[2];
  const float* proj_w = (const float*)d_in[3];
  const float* proj_b = (const float*)d_in[4];
  float* out = (float*)d_out;

  float* ws = (float*)d_ws;
  float* t_mean = ws;                                       // [0, 65536)
  float* q0k0_part = ws + 65536;                            // [65536, 589824)
  float* u = ws + 589824;                                   // [589824, 1114112)
  float* out0_part = ws + 1114112;                          // [1114112, 1376256)
  float* out_part = ws + 1376256;                           // [1376256, 1638400)
  float2* sc = (float2*)(ws + 1638400);                     // [1638400, 1671168)
  unsigned short* wkT = (unsigned short*)(ws + 1671168);    // 1179648 u16 = [1671168, 2260992)
  unsigned short* T = (unsigned short*)(ws + 2260992);      // 18874368 u16 = [2260992, 11698176)
  unsigned short* x_t = (unsigned short*)(ws + 11698176);   // 16777216 u16 = [11698176, 20086784)

  // 1. fused prep: x->x_t+mean | wkT transpose | wkT bias rows | sc table
  prep_kernel<<<1352, 256, 0, stream>>>(x, qkv_w, qkv_b, x_t, t_mean, wkT, sc);

  // 2. q0k0 partials: t_mean @ qkv_w[0:2048].T  (M=64,N=2048,K=4x256)
  gemm_splitk<<<dim3(32, 2, 4), 256, 0, stream>>>(t_mean, 1024, 0, qkv_w, 1024, 0,
                                                  q0k0_part, 2048, 0, 131072, 4);

  // 3. T = rotated-q0 @ WkT (factorized RoPE; M=1024,N=1152,K=64, per h,half)
  tgemm_rot<<<dim3(9, 8, 16), 256, 0, stream>>>(wkT, q0k0_part, qkv_b, sc, T);

  // 4. MFMA scores + softmax + u  (256 blocks = (b, head-pair), 8 waves, BK=64)
  scores_u<<<256, 512, 0, stream>>>(T, x_t, q0k0_part, qkv_b, t_mean, u);

  // 5. out0 partials: per-head Wv_h . u  (Z=8, K=4x256)
  gemm_splitk<<<dim3(2, 2, 32), 256, 0, stream>>>(u, 8192, 1024,
                                                  qkv_w + (size_t)2048 * 1024, 1024, 131072,
                                                  out0_part, 1024, 128, 65536, 4);

  // 6. proj partials, A = reduce4(out0_part)+bias_v inline
  gemm_proj_splitk<<<dim3(16, 2, 4), 256, 0, stream>>>(out0_part, qkv_b + 2048, proj_w, out_part);

  // 7. final reduce + proj bias
  reduce4_bias<<<256, 256, 0, stream>>>(out_part, proj_b, out);
}

// Round 12
// 95.752 us; speedup vs baseline: 1.6728x; 1.0462x over previous
//
#include <hip/hip_runtime.h>
#include <math.h>

#define PI_F 3.14159265358979323846f
#define KSTEP 0.21959209425992272f /* (log2(224)-1)/31 */

using bf16x8 = __attribute__((ext_vector_type(8))) short;
using f32x4 = __attribute__((ext_vector_type(4))) float;
using u16x8 = __attribute__((ext_vector_type(8))) unsigned short;

static __device__ __forceinline__ float wave_reduce_sum(float v) {
#pragma unroll
  for (int off = 32; off; off >>= 1) v += __shfl_down(v, off);
  return v;
}

static __device__ __forceinline__ unsigned short f2bf(float f) {
  unsigned u = __float_as_uint(f);
  return (unsigned short)((u + 0x7fffu + ((u >> 16) & 1u)) >> 16);
}

static __device__ __forceinline__ float bf2f(unsigned short s) {
  return __uint_as_float(((unsigned)s) << 16);
}

static __device__ __forceinline__ void gload_lds16(const void* g, void* l) {
  __builtin_amdgcn_global_load_lds((const __attribute__((address_space(1))) unsigned int*)g,
                                   (__attribute__((address_space(3))) unsigned int*)l, 16, 0, 0);
}

// ---- fused prep: x->bf16 x_t + t_mean | wkT (transposed Wk) | sc table ----
__global__ __launch_bounds__(256) void prep_kernel(const float* __restrict__ x,
                                                   const float* __restrict__ qkv_w,
                                                   const float* __restrict__ qkv_b,
                                                   unsigned short* __restrict__ xt,
                                                   float* __restrict__ t_mean,
                                                   unsigned short* __restrict__ wkT,
                                                   float2* __restrict__ sc) {
  const int bid = blockIdx.x;
  const int t = threadIdx.x;
  __shared__ float tile[64 * 33];
  __shared__ float tl2[64 * 65];
  if (bid < 1024) {
    const int ct = bid & 15, b = bid >> 4;
    const int cl = t >> 2, pq = (t & 3) * 8;  // read role
    const int pl = t >> 3, cq = (t & 7) * 8;  // write role
    float sum = 0.0f;
    const float* xrow = x + ((size_t)(b * 1024 + ct * 64 + cl) * 256) + pq;
    unsigned short* xtb = xt + (size_t)b * 262144 + ct * 64;
    for (int pt = 0; pt < 8; ++pt) {
      const float4 v0 = *reinterpret_cast<const float4*>(xrow + pt * 32);
      const float4 v1 = *reinterpret_cast<const float4*>(xrow + pt * 32 + 4);
      tile[cl * 33 + pq + 0] = v0.x; tile[cl * 33 + pq + 1] = v0.y;
      tile[cl * 33 + pq + 2] = v0.z; tile[cl * 33 + pq + 3] = v0.w;
      tile[cl * 33 + pq + 4] = v1.x; tile[cl * 33 + pq + 5] = v1.y;
      tile[cl * 33 + pq + 6] = v1.z; tile[cl * 33 + pq + 7] = v1.w;
      sum += (v0.x + v0.y) + (v0.z + v0.w) + (v1.x + v1.y) + (v1.z + v1.w);
      __syncthreads();
      u16x8 o;
#pragma unroll
      for (int e = 0; e < 8; ++e) o[e] = f2bf(tile[(cq + e) * 33 + pl]);
      *reinterpret_cast<u16x8*>(xtb + (size_t)(pt * 32 + pl) * 1024 + cq) = o;
      __syncthreads();
    }
    sum += __shfl_xor(sum, 1);
    sum += __shfl_xor(sum, 2);
    if ((t & 3) == 0) t_mean[b * 1024 + ct * 64 + cl] = sum * (1.0f / 256.0f);
  } else if (bid < 1280) {
    // wkT[h][c][d] transpose tiles: bf16, c rows, d contiguous
    const int bb = bid - 1024;
    const int h = bb >> 5, t5 = bb & 31;
    const int dt = t5 >> 4, ct = t5 & 15;
    {
      const int dl = t >> 2, cq = (t & 3) * 16;
      const float* src = qkv_w + (size_t)(1024 + h * 128 + dt * 64 + dl) * 1024 + ct * 64 + cq;
#pragma unroll
      for (int i = 0; i < 4; ++i) {
        const float4 v = *reinterpret_cast<const float4*>(src + i * 4);
        tl2[dl * 65 + cq + i * 4 + 0] = v.x; tl2[dl * 65 + cq + i * 4 + 1] = v.y;
        tl2[dl * 65 + cq + i * 4 + 2] = v.z; tl2[dl * 65 + cq + i * 4 + 3] = v.w;
      }
    }
    __syncthreads();
    {
      const int cl = t >> 2, dq = (t & 3) * 16;
      unsigned short* dst = wkT + (size_t)(h * 1152 + ct * 64 + cl) * 128 + dt * 64 + dq;
      u16x8 o0, o1;
#pragma unroll
      for (int e = 0; e < 8; ++e) {
        o0[e] = f2bf(tl2[(dq + e) * 65 + cl]);
        o1[e] = f2bf(tl2[(dq + 8 + e) * 65 + cl]);
      }
      *reinterpret_cast<u16x8*>(dst) = o0;
      *reinterpret_cast<u16x8*>(dst + 8) = o1;
    }
  } else {
    const int idx = (bid - 1280) * 256 + t;  // 16384
    const int m = idx >> 8, j = idx & 255;
    const float band = exp2f((float)(m & 31) * KSTEP) * PI_F;
    const float coord = (m < 32) ? (-1.0f + (2.0f / 15.0f) * (float)(j >> 4))
                                 : (-1.0f + (2.0f / 15.0f) * (float)(j & 15));
    float sn, cs;
    sincosf(coord * band, &sn, &cs);
    sc[idx] = make_float2(sn, cs);
  }
}

// ---------------- split-K skinny GEMM: Cp[kc] = A * B^T (K-chunk = 256) ----------------
__global__ __launch_bounds__(256) void gemm_splitk(
    const float* __restrict__ A, int lda, int aStrideZ,
    const float* __restrict__ B, int ldb, int bStrideZ,
    float* __restrict__ Cp, int ldc, int cStrideZ, int cStrideKc, int KC) {
  const int nt = blockIdx.x, mt = blockIdx.y;
  const int z = blockIdx.z / KC, kc = blockIdx.z % KC;
  const int tid = threadIdx.x;
  A += (size_t)z * aStrideZ + (size_t)mt * 32 * lda + kc * 256;
  B += (size_t)z * bStrideZ + (size_t)nt * 64 * ldb + kc * 256;
  Cp += (size_t)kc * cStrideKc + (size_t)z * cStrideZ + (size_t)mt * 32 * ldc + nt * 64;

  __shared__ float As[32][34];
  __shared__ float Bs[32][68];

  const int tm = tid >> 4;
  const int tn = tid & 15;
  float acc0[4] = {0, 0, 0, 0}, acc1[4] = {0, 0, 0, 0};

  for (int k0 = 0; k0 < 256; k0 += 32) {
    {
      const int m = tid >> 3, kq = tid & 7;
      float4 v = *reinterpret_cast<const float4*>(A + (size_t)m * lda + k0 + kq * 4);
      As[kq * 4 + 0][m] = v.x; As[kq * 4 + 1][m] = v.y;
      As[kq * 4 + 2][m] = v.z; As[kq * 4 + 3][m] = v.w;
    }
#pragma unroll
    for (int r = 0; r < 2; ++r) {
      const int idx = r * 256 + tid;
      const int n = idx >> 3, kq = idx & 7;
      float4 v = *reinterpret_cast<const float4*>(B + (size_t)n * ldb + k0 + kq * 4);
      Bs[kq * 4 + 0][n] = v.x; Bs[kq * 4 + 1][n] = v.y;
      Bs[kq * 4 + 2][n] = v.z; Bs[kq * 4 + 3][n] = v.w;
    }
    __syncthreads();
#pragma unroll
    for (int k = 0; k < 32; ++k) {
      const float a0 = As[k][tm * 2], a1 = As[k][tm * 2 + 1];
      const float4 bb = *reinterpret_cast<const float4*>(&Bs[k][tn * 4]);
      acc0[0] += a0 * bb.x; acc0[1] += a0 * bb.y; acc0[2] += a0 * bb.z; acc0[3] += a0 * bb.w;
      acc1[0] += a1 * bb.x; acc1[1] += a1 * bb.y; acc1[2] += a1 * bb.z; acc1[3] += a1 * bb.w;
    }
    __syncthreads();
  }
  *reinterpret_cast<float4*>(Cp + (size_t)(tm * 2) * ldc + tn * 4) =
      make_float4(acc0[0], acc0[1], acc0[2], acc0[3]);
  *reinterpret_cast<float4*>(Cp + (size_t)(tm * 2 + 1) * ldc + tn * 4) =
      make_float4(acc1[0], acc1[1], acc1[2], acc1[3]);
}

// ---------------- proj GEMM with inline 4-partial A reduce + Wv-bias ----------------
__global__ __launch_bounds__(256) void gemm_proj_splitk(
    const float* __restrict__ Apart, const float* __restrict__ abias,
    const float* __restrict__ B, float* __restrict__ Cp) {
  const int nt = blockIdx.x, mt = blockIdx.y, kc = blockIdx.z;
  const int tid = threadIdx.x;
  B += (size_t)nt * 64 * 1024 + kc * 256;
  Cp += (size_t)kc * 65536 + (size_t)mt * 32 * 1024 + nt * 64;

  __shared__ float As[32][34];
  __shared__ float Bs[32][68];

  const int tm = tid >> 4;
  const int tn = tid & 15;
  float acc0[4] = {0, 0, 0, 0}, acc1[4] = {0, 0, 0, 0};

  for (int k0 = 0; k0 < 256; k0 += 32) {
    {
      const int m = tid >> 3, kq = tid & 7;
      const int kg = kc * 256 + k0 + kq * 4;
      const float* Ab = Apart + (size_t)(mt * 32 + m) * 1024 + kg;
      float4 v = *reinterpret_cast<const float4*>(abias + kg);
#pragma unroll
      for (int r = 0; r < 4; ++r) {
        const float4 p = *reinterpret_cast<const float4*>(Ab + (size_t)r * 65536);
        v.x += p.x; v.y += p.y; v.z += p.z; v.w += p.w;
      }
      As[kq * 4 + 0][m] = v.x; As[kq * 4 + 1][m] = v.y;
      As[kq * 4 + 2][m] = v.z; As[kq * 4 + 3][m] = v.w;
    }
#pragma unroll
    for (int r = 0; r < 2; ++r) {
      const int idx = r * 256 + tid;
      const int n = idx >> 3, kq = idx & 7;
      float4 v = *reinterpret_cast<const float4*>(B + (size_t)n * 1024 + k0 + kq * 4);
      Bs[kq * 4 + 0][n] = v.x; Bs[kq * 4 + 1][n] = v.y;
      Bs[kq * 4 + 2][n] = v.z; Bs[kq * 4 + 3][n] = v.w;
    }
    __syncthreads();
#pragma unroll
    for (int k = 0; k < 32; ++k) {
      const float a0 = As[k][tm * 2], a1 = As[k][tm * 2 + 1];
      const float4 bb = *reinterpret_cast<const float4*>(&Bs[k][tn * 4]);
      acc0[0] += a0 * bb.x; acc0[1] += a0 * bb.y; acc0[2] += a0 * bb.z; acc0[3] += a0 * bb.w;
      acc1[0] += a1 * bb.x; acc1[1] += a1 * bb.y; acc1[2] += a1 * bb.z; acc1[3] += a1 * bb.w;
    }
    __syncthreads();
  }
  *reinterpret_cast<float4*>(Cp + (size_t)(tm * 2) * 1024 + tn * 4) =
      make_float4(acc0[0], acc0[1], acc0[2], acc0[3]);
  *reinterpret_cast<float4*>(Cp + (size_t)(tm * 2 + 1) * 1024 + tn * 4) =
      make_float4(acc1[0], acc1[1], acc1[2], acc1[3]);
}

// ---------------- reduce 4 split-K partials + bias ----------------
__global__ __launch_bounds__(256) void reduce4_bias(const float* __restrict__ part,
                                                    const float* __restrict__ bias,
                                                    float* __restrict__ out) {
  const int i = blockIdx.x * 256 + threadIdx.x;  // 65536
  out[i] = part[i] + part[i + 65536] + part[i + 131072] + part[i + 196608] + bias[i & 1023];
}

// ---------------- MFMA scores + fused T-gen + softmax + u ----------------
// Block (b, ht): per c-chunk (BK=64): stage x_t A-panel + wkT chunk; generate
// B-tile = rotq @ wkT_chunk^T in-block (MFMA, bf16); main P-GEMM; then diag
// extraction + exact bias + softmax + u. No T round-trip to HBM.
__global__ __launch_bounds__(512, 1) void scores_u(
    const unsigned short* __restrict__ wkT, const unsigned short* __restrict__ xt,
    const float* __restrict__ q0p, const float* __restrict__ qkv_b,
    const float2* __restrict__ sc, const float* __restrict__ t_mean,
    float* __restrict__ u) {
  const int l = blockIdx.x;  // 256; same-b blocks share an XCD (l&7 preserved)
  const int b = ((l >> 5) << 3) | (l & 7);
  const int ht = (l >> 3) & 3;  // head pair: heads ht*2, ht*2+1
  const int tid = threadIdx.x;
  const int w = tid >> 6, lane = tid & 63;
  const int rgrp = lane >> 4;

  // B-gen wave roles: combo kap = hh*2+s, c-half ch
  const int hh_ = w >> 2, sgen = (w >> 1) & 1, ch = w & 1;
  const int kap = hh_ * 2 + sgen;

  __shared__ __align__(16) char smem[143872];
  // [0,65536): A bufs (2 x 32KB, x_t)   [65536,131072): W bufs (2 x 32KB, wkT)
  // [131072,139264): Btile (64n x 128B)  [139264,...): persist
  float* persist = reinterpret_cast<float*>(smem + 139264);
  float* q0l = persist;          // [256]
  float* k0l = persist + 256;    // [256]
  float* biasg = persist + 512;  // [64]
  float* ps = persist + 576;     // [4]
  float* smax = persist + 580;   // [8]
  float* ssum = persist + 588;   // [8]
  float* attnl = persist + 596;  // [2][257]
  char* Btile = smem + 131072;

  const unsigned short* xtb = xt + (size_t)b * 262144;

#define STAGE_A(buf, c0)                                                        \
  {                                                                             \
    char* Ab_ = smem + (buf)*32768;                                             \
    _Pragma("unroll") for (int i = 0; i < 4; ++i) {                             \
      const int row_ = w * 32 + i * 8 + (lane >> 3);                            \
      const int sl_ = ((lane & 7) ^ ((row_ >> 1) & 7)) * 8;                     \
      gload_lds16(xtb + (size_t)row_ * 1024 + (c0) + sl_,                       \
                  Ab_ + (w * 4 + i) * 1024);                                    \
    }                                                                           \
  }
#define STAGE_W(buf, c0)                                                        \
  {                                                                             \
    char* Wb_ = smem + 65536 + (buf)*32768;                                     \
    _Pragma("unroll") for (int i = 0; i < 4; ++i) {                             \
      const int r_ = w * 16 + i * 4 + (lane >> 4); /* h*64+c */                 \
      const int c_ = r_ & 63;                                                   \
      const int L_ = lane & 15;                                                 \
      const int so_ = (L_ >> 3) * 64 + ((L_ & 7) ^ ((c_ >> 1) & 7)) * 8;        \
      gload_lds16(wkT + ((size_t)(ht * 2 + (r_ >> 6)) * 1152 + (c0) + c_) * 128 \
                      + so_,                                                    \
                  Wb_ + (w * 16 + i * 4) * 256);                                \
    }                                                                           \
  }

  // prologue: stage tile 0; q0/k0 reduce; rotq registers
  STAGE_A(0, 0);
  STAGE_W(0, 0);
  if (tid < 256) {
    const float* qp = q0p + (size_t)b * 2048 + ht * 256 + tid;
    q0l[tid] = qkv_b[ht * 256 + tid] + qp[0] + qp[131072] + qp[262144] + qp[393216];
    const float* kp = qp + 1024;
    k0l[tid] = qkv_b[1024 + ht * 256 + tid] + kp[0] + kp[131072] + kp[262144] + kp[393216];
  }
  __syncthreads();  // q0l visible; drains prologue gloads (ok, once)

  // rotq fragments in registers: rq[kk][e] = rot(v=lane&15, d=kk*32+rgrp*8+e)
  bf16x8 rq[2];
  {
    const int v = lane & 15;
    const int jrep = sgen ? v : v * 16;
#pragma unroll
    for (int kk = 0; kk < 2; ++kk) {
#pragma unroll
      for (int e = 0; e < 8; e += 2) {
        const int d = kk * 32 + rgrp * 8 + e;
        const int p = d >> 1;
        const float qe = q0l[hh_ * 128 + sgen * 64 + 2 * p];
        const float qo = q0l[hh_ * 128 + sgen * 64 + 2 * p + 1];
        const float2 tt = sc[(sgen * 32 + p) * 256 + jrep];
        rq[kk][e] = (short)f2bf(qe * tt.y + qo * tt.x);
        rq[kk][e + 1] = (short)f2bf(qo * tt.y - qe * tt.x);
      }
    }
  }

  f32x4 acc[2][4] = {};
  for (int t = 0; t < 16; ++t) {
    {  // stage tile t+1 (clamped tail keeps vmcnt uniform)
      const int src = (t + 1 > 15) ? 15 : (t + 1);
      STAGE_A((t + 1) & 1, src * 64);
      STAGE_W((t + 1) & 1, src * 64);
    }
    asm volatile("s_waitcnt vmcnt(8)" ::: "memory");  // tile t resident
    __builtin_amdgcn_s_barrier();
    const char* Ab = smem + (t & 1) * 32768;
    const char* Wb = smem + 65536 + (t & 1) * 32768;
    // ---- B-gen: Btile[n= kap*16+v][c] = sum_d wkT[c][d] * rotq[n][d]
    {
      f32x4 accg[2] = {};
#pragma unroll
      for (int kk = 0; kk < 2; ++kk) {
#pragma unroll
        for (int mt = 0; mt < 2; ++mt) {
          const int c_ = ch * 32 + mt * 16 + (lane & 15);
          const int slot = sgen * 8 + (((kk * 4 + rgrp)) ^ ((c_ >> 1) & 7));
          const bf16x8 wf = *reinterpret_cast<const bf16x8*>(
              Wb + (hh_ * 64 + c_) * 256 + (slot << 4));
          accg[mt] = __builtin_amdgcn_mfma_f32_16x16x32_bf16(wf, rq[kk], accg[mt], 0, 0, 0);
        }
      }
#pragma unroll
      for (int mt = 0; mt < 2; ++mt) {
        const int cl = ch * 32 + mt * 16 + rgrp * 4;
        const int n = kap * 16 + (lane & 15);
        const unsigned u0 = (unsigned)f2bf(accg[mt][0]) | ((unsigned)f2bf(accg[mt][1]) << 16);
        const unsigned u1 = (unsigned)f2bf(accg[mt][2]) | ((unsigned)f2bf(accg[mt][3]) << 16);
        *reinterpret_cast<uint2*>(Btile + n * 128 + ((((cl >> 3) ^ ((n >> 1) & 7))) << 4) +
                                  (rgrp & 1) * 8) = make_uint2(u0, u1);
      }
    }
    asm volatile("s_waitcnt lgkmcnt(0)" ::: "memory");
    __builtin_amdgcn_s_barrier();  // Btile ready
    // ---- main P-GEMM
#pragma unroll
    for (int kk = 0; kk < 2; ++kk) {
      bf16x8 af[2], bfr[4];
#pragma unroll
      for (int mi = 0; mi < 2; ++mi) {
        const int row = w * 32 + mi * 16 + (lane & 15);
        const int slot = (kk * 4 + rgrp) ^ ((row >> 1) & 7);
        af[mi] = *reinterpret_cast<const bf16x8*>(Ab + row * 128 + (slot << 4));
      }
#pragma unroll
      for (int ni = 0; ni < 4; ++ni) {
        const int n = ni * 16 + (lane & 15);
        const int slot = (kk * 4 + rgrp) ^ ((n >> 1) & 7);
        bfr[ni] = *reinterpret_cast<const bf16x8*>(Btile + n * 128 + (slot << 4));
      }
      __builtin_amdgcn_s_setprio(1);
#pragma unroll
      for (int mi = 0; mi < 2; ++mi)
#pragma unroll
        for (int ni = 0; ni < 4; ++ni)
          acc[mi][ni] =
              __builtin_amdgcn_mfma_f32_16x16x32_bf16(af[mi], bfr[ni], acc[mi][ni], 0, 0, 0);
      __builtin_amdgcn_s_setprio(0);
    }
    __builtin_amdgcn_s_barrier();  // readers done before next iter overwrites
    asm volatile("" ::: "memory");
  }
#undef STAGE_A
#undef STAGE_W

  asm volatile("s_waitcnt vmcnt(0)" ::: "memory");
  __syncthreads();

  // ---- epilogue arrays (reuse low LDS) ----
  float* Sp = reinterpret_cast<float*>(smem);  // [256 j][2 h][2 s]
  float* upart = reinterpret_cast<float*>(smem + 16384);  // [8 w][2 h][1024 c]

  // diagonal extraction: each (j, h, s) slot has exactly one writer lane
#pragma unroll
  for (int mi = 0; mi < 2; ++mi)
#pragma unroll
    for (int ni = 0; ni < 4; ++ni)
#pragma unroll
      for (int rr = 0; rr < 4; ++rr) {
        const int j = w * 32 + mi * 16 + (rgrp << 2) + rr;
        const int col = ni * 16 + (lane & 15);
        const int s = (col >> 4) & 1;
        const int sel = s ? (j & 15) : (j >> 4);
        if ((col & 15) == sel) Sp[(j * 2 + (col >> 5)) * 2 + s] = acc[mi][ni][rr];
      }
  // exact bias: biasg[h*32+s*16+v] = rot_v(q0_half) . k_bias_half
  if (tid < 64) {
    const int h_ = tid >> 5, s_ = (tid >> 4) & 1, v_ = tid & 15;
    const float* bk = qkv_b + 1024 + (ht * 2 + h_) * 128 + s_ * 64;
    const int jrep = s_ ? v_ : v_ * 16;
    float a = 0.0f;
#pragma unroll 4
    for (int p = 0; p < 32; ++p) {
      const float qe = q0l[h_ * 128 + s_ * 64 + 2 * p];
      const float qo = q0l[h_ * 128 + s_ * 64 + 2 * p + 1];
      const float2 tt = sc[(s_ * 32 + p) * 256 + jrep];
      a += (qe * tt.y + qo * tt.x) * bk[2 * p] + (qo * tt.y - qe * tt.x) * bk[2 * p + 1];
    }
    biasg[tid] = a;
  }
  if (tid < 256) {
    float pr = q0l[tid] * k0l[tid];
    pr = wave_reduce_sum(pr);
    if (lane == 0) ps[w] = pr;  // w 0,1 -> head0; 2,3 -> head1
  }
  __syncthreads();

  // ---- dual-head softmax over 257 tokens (threads 0..255; tid0 also token 0)
  const float scale = 0.08838834764831845f;
  float e0 = 0.0f, e1 = 0.0f, eb0 = 0.0f, eb1 = 0.0f;
  if (tid < 256) {
    const float va0 = scale * (Sp[tid * 4 + 0] + Sp[tid * 4 + 1] + biasg[tid >> 4] +
                               biasg[16 + (tid & 15)]);
    const float va1 = scale * (Sp[tid * 4 + 2] + Sp[tid * 4 + 3] + biasg[32 + (tid >> 4)] +
                               biasg[48 + (tid & 15)]);
    float vb0 = -3.0e38f, vb1 = -3.0e38f;
    if (tid == 0) {
      vb0 = scale * (ps[0] + ps[1]);
      vb1 = scale * (ps[2] + ps[3]);
    }
    float m0 = fmaxf(va0, vb0), m1 = fmaxf(va1, vb1);
#pragma unroll
    for (int off = 32; off; off >>= 1) {
      m0 = fmaxf(m0, __shfl_xor(m0, off));
      m1 = fmaxf(m1, __shfl_xor(m1, off));
    }
    if (lane == 0) { smax[w] = m0; smax[4 + w] = m1; }
  }
  __syncthreads();
  if (tid < 256) {
    const float g0 = fmaxf(fmaxf(smax[0], smax[1]), fmaxf(smax[2], smax[3]));
    const float g1 = fmaxf(fmaxf(smax[4], smax[5]), fmaxf(smax[6], smax[7]));
    const float va0 = scale * (Sp[tid * 4 + 0] + Sp[tid * 4 + 1] + biasg[tid >> 4] +
                               biasg[16 + (tid & 15)]);
    const float va1 = scale * (Sp[tid * 4 + 2] + Sp[tid * 4 + 3] + biasg[32 + (tid >> 4)] +
                               biasg[48 + (tid & 15)]);
    e0 = expf(va0 - g0);
    e1 = expf(va1 - g1);
    if (tid == 0) {
      eb0 = expf(scale * (ps[0] + ps[1]) - g0);
      eb1 = expf(scale * (ps[2] + ps[3]) - g1);
    }
    float s0 = e0 + eb0, s1 = e1 + eb1;
#pragma unroll
    for (int off = 32; off; off >>= 1) {
      s0 += __shfl_xor(s0, off);
      s1 += __shfl_xor(s1, off);
    }
    if (lane == 0) { ssum[w] = s0; ssum[4 + w] = s1; }
  }
  __syncthreads();
  if (tid < 256) {
    const float inv0 = 1.0f / (ssum[0] + ssum[1] + ssum[2] + ssum[3]);
    const float inv1 = 1.0f / (ssum[4] + ssum[5] + ssum[6] + ssum[7]);
    attnl[1 + tid] = e0 * inv0;
    attnl[257 + 1 + tid] = e1 * inv1;
    if (tid == 0) { attnl[0] = eb0 * inv0; attnl[257] = eb1 * inv1; }
  }
  __syncthreads();

  // ---- u: wave w accumulates its 32 j over all 1024 c (lane owns 16 c)
  {
    float ua0[16] = {}, ua1[16] = {};
    const unsigned short* xr = xtb + (size_t)(w * 32) * 1024 + lane * 16;
    for (int jj = 0; jj < 32; ++jj) {
      const float a0 = attnl[1 + w * 32 + jj];
      const float a1 = attnl[257 + 1 + w * 32 + jj];
      const u16x8 v0 = *reinterpret_cast<const u16x8*>(xr + (size_t)jj * 1024);
      const u16x8 v1 = *reinterpret_cast<const u16x8*>(xr + (size_t)jj * 1024 + 8);
#pragma unroll
      for (int e = 0; e < 8; ++e) {
        const float f0 = bf2f((unsigned short)v0[e]);
        const float f1 = bf2f((unsigned short)v1[e]);
        ua0[e] += a0 * f0; ua0[8 + e] += a0 * f1;
        ua1[e] += a1 * f0; ua1[8 + e] += a1 * f1;
      }
    }
#pragma unroll
    for (int e = 0; e < 16; ++e) {
      upart[(w * 2 + 0) * 1024 + lane * 16 + e] = ua0[e];
      upart[(w * 2 + 1) * 1024 + lane * 16 + e] = ua1[e];
    }
  }
  __syncthreads();
#pragma unroll
  for (int r = 0; r < 4; ++r) {
    const int o = tid * 4 + r;  // 0..2047
    const int h2 = o >> 10, c = o & 1023;
    float s = 0.0f;
#pragma unroll
    for (int ww = 0; ww < 8; ++ww) s += upart[(ww * 2 + h2) * 1024 + c];
    s += attnl[h2 * 257] * t_mean[b * 1024 + c];
    u[((size_t)b * 8 + ht * 2 + h2) * 1024 + c] = s;
  }
}

// ---------------- host side ----------------
extern "C" void kernel_launch(void* const* d_in, const int* in_sizes, int n_in,
                              void* d_out, int out_size, void* d_ws, size_t ws_size,
                              hipStream_t stream) {
  const float* x = (const float*)d_in[0];
  const float* qkv_w = (const float*)d_in[1];
  const float* qkv_b = (const float*)d_in[2];
  const float* proj_w = (const float*)d_in[3];
  const float* proj_b = (const float*)d_in[4];
  float* out = (float*)d_out;

  float* ws = (float*)d_ws;
  float* t_mean = ws;                                       // [0, 65536)
  float* q0k0_part = ws + 65536;                            // [65536, 589824)
  float* u = ws + 589824;                                   // [589824, 1114112)
  float* out0_part = ws + 1114112;                          // [1114112, 1376256)
  float* out_part = ws + 1376256;                           // [1376256, 1638400)
  float2* sc = (float2*)(ws + 1638400);                     // [1638400, 1671168)
  unsigned short* wkT = (unsigned short*)(ws + 1671168);    // 1179648 u16
  unsigned short* x_t = (unsigned short*)(ws + 11698176);   // 16777216 u16

  // 1. fused prep: x->x_t+mean (1024) | wkT transpose (256) | sc table (64)
  prep_kernel<<<1344, 256, 0, stream>>>(x, qkv_w, qkv_b, x_t, t_mean, wkT, sc);

  // 2. q0k0 partials: t_mean @ qkv_w[0:2048].T  (M=64,N=2048,K=4x256)
  gemm_splitk<<<dim3(32, 2, 4), 256, 0, stream>>>(t_mean, 1024, 0, qkv_w, 1024, 0,
                                                  q0k0_part, 2048, 0, 131072, 4);

  // 3. MFMA scores + in-block T-gen + softmax + u  (256 blocks, 8 waves)
  scores_u<<<256, 512, 0, stream>>>(wkT, x_t, q0k0_part, qkv_b, sc, t_mean, u);

  // 4. out0 partials: per-head Wv_h . u  (Z=8, K=4x256)
  gemm_splitk<<<dim3(2, 2, 32), 256, 0, stream>>>(u, 8192, 1024,
                                                  qkv_w + (size_t)2048 * 1024, 1024, 131072,
                                                  out0_part, 1024, 128, 65536, 4);

  // 5. proj partials, A = reduce4(out0_part)+bias_v inline
  gemm_proj_splitk<<<dim3(16, 2, 4), 256, 0, stream>>>(out0_part, qkv_b + 2048, proj_w, out_part);

  // 6. final reduce + proj bias
  reduce4_bias<<<256, 256, 0, stream>>>(out_part, proj_b, out);
}